// Round 1
// baseline (2549.933 us; speedup 1.0000x reference)
//
#include <hip/hip_runtime.h>
#include <cstddef>
#include <cstdint>

#define BM 128
#define BN 128
#define BK 16

// C[M,Nc] = A[M,K] @ op(B) + bias ; op(B)=B [K,Nc] (TRANS_B=false) or B^T with B [Nc,K] (TRANS_B=true)
template<bool TRANS_B>
__global__ __launch_bounds__(256)
void sgemm_bias(const float* __restrict__ A, const float* __restrict__ B,
                const float* __restrict__ bias, float* __restrict__ C,
                int M, int Nc, int K)
{
    __shared__ float As[BK][BM + 4];
    __shared__ float Bs[BK][BN + 4];
    const int t  = threadIdx.x;
    const int tx = t & 15, ty = t >> 4;
    const int row0 = blockIdx.y * BM;
    const int col0 = blockIdx.x * BN;

    float acc[8][8];
#pragma unroll
    for (int i = 0; i < 8; ++i)
#pragma unroll
        for (int j = 0; j < 8; ++j) acc[i][j] = 0.0f;

    for (int k0 = 0; k0 < K; k0 += BK) {
        // A tile: 128 rows x 16 k, 512 float4 quads
#pragma unroll
        for (int qq = 0; qq < 2; ++qq) {
            int q = t + qq * 256;
            int row = q >> 2, kq = q & 3;
            float4 v = make_float4(0.f, 0.f, 0.f, 0.f);
            if (row0 + row < M)
                v = *(const float4*)&A[(size_t)(row0 + row) * K + k0 + kq * 4];
            As[kq * 4 + 0][row] = v.x;
            As[kq * 4 + 1][row] = v.y;
            As[kq * 4 + 2][row] = v.z;
            As[kq * 4 + 3][row] = v.w;
        }
        if (TRANS_B) {
#pragma unroll
            for (int qq = 0; qq < 2; ++qq) {
                int q = t + qq * 256;
                int col = q >> 2, kq = q & 3;
                float4 v = *(const float4*)&B[(size_t)(col0 + col) * K + k0 + kq * 4];
                Bs[kq * 4 + 0][col] = v.x;
                Bs[kq * 4 + 1][col] = v.y;
                Bs[kq * 4 + 2][col] = v.z;
                Bs[kq * 4 + 3][col] = v.w;
            }
        } else {
#pragma unroll
            for (int qq = 0; qq < 2; ++qq) {
                int q = t + qq * 256;
                int kk = q >> 5, nq = q & 31;
                float4 v = *(const float4*)&B[(size_t)(k0 + kk) * Nc + col0 + nq * 4];
                *(float4*)&Bs[kk][nq * 4] = v;
            }
        }
        __syncthreads();
#pragma unroll
        for (int kk = 0; kk < BK; ++kk) {
            float a[8], b[8];
            *(float4*)&a[0] = *(const float4*)&As[kk][ty * 8];
            *(float4*)&a[4] = *(const float4*)&As[kk][ty * 8 + 4];
            *(float4*)&b[0] = *(const float4*)&Bs[kk][tx * 8];
            *(float4*)&b[4] = *(const float4*)&Bs[kk][tx * 8 + 4];
#pragma unroll
            for (int i = 0; i < 8; ++i)
#pragma unroll
                for (int j = 0; j < 8; ++j)
                    acc[i][j] = fmaf(a[i], b[j], acc[i][j]);
        }
        __syncthreads();
    }

#pragma unroll
    for (int i = 0; i < 8; ++i) {
        int r = row0 + ty * 8 + i;
        if (r < M) {
#pragma unroll
            for (int j = 0; j < 8; ++j) {
                int c = col0 + tx * 8 + j;
                float bv = bias ? bias[c] : 0.0f;
                C[(size_t)r * Nc + c] = acc[i][j] + bv;
            }
        }
    }
}

// one wave per edge: agg[dst] += m[src]  (H=128, float2 per lane)
__global__ __launch_bounds__(256)
void scatter_add_kernel(const float* __restrict__ m, const int* __restrict__ src,
                        const int* __restrict__ dst, float* __restrict__ agg, int E)
{
    int w = (blockIdx.x * 256 + threadIdx.x) >> 6;
    int lane = threadIdx.x & 63;
    if (w >= E) return;
    int s = src[w], d = dst[w];
    float2 v = *(const float2*)&m[(size_t)s * 128 + lane * 2];
    atomicAdd(&agg[(size_t)d * 128 + lane * 2], v.x);
    atomicAdd(&agg[(size_t)d * 128 + lane * 2 + 1], v.y);
}

// GRUCell elementwise: gi/gh are [N,384], hin [N,128] ; H=128 hard-coded
__global__ __launch_bounds__(256)
void gru_kernel(const float* __restrict__ gi, const float* __restrict__ gh,
                const float* __restrict__ hin, float* __restrict__ hout,
                int NHtot, int applyElu)
{
    int idx = blockIdx.x * 256 + threadIdx.x;
    if (idx >= NHtot) return;
    int n = idx >> 7;
    int j = idx & 127;
    size_t base = (size_t)n * 384 + j;
    float ir = gi[base], iz = gi[base + 128], in_ = gi[base + 256];
    float hr = gh[base], hz = gh[base + 128], hn = gh[base + 256];
    float hv = hin[idx];
    float r = 1.0f / (1.0f + expf(-(ir + hr)));
    float z = 1.0f / (1.0f + expf(-(iz + hz)));
    float nn = tanhf(in_ + r * hn);
    float o = (1.0f - z) * nn + z * hv;
    if (applyElu) o = (o > 0.0f) ? o : expm1f(o);
    hout[idx] = o;
}

// one wave per node: logits = h@W + b ; log_softmax ; loss += (lse - logit[y])/N
__global__ __launch_bounds__(256)
void cls_kernel(const float* __restrict__ h, const float* __restrict__ W,
                const float* __restrict__ b, const int* __restrict__ y,
                float* __restrict__ logitsOut, float* __restrict__ lossOut,
                int N, float invN)
{
    int gw = (blockIdx.x * 256 + threadIdx.x) >> 6;
    int lane = threadIdx.x & 63;
    if (gw >= N) return;
    float h0 = h[(size_t)gw * 128 + lane * 2];
    float h1 = h[(size_t)gw * 128 + lane * 2 + 1];
    float acc[6];
#pragma unroll
    for (int c = 0; c < 6; ++c)
        acc[c] = h0 * W[(lane * 2) * 6 + c] + h1 * W[(lane * 2 + 1) * 6 + c];
#pragma unroll
    for (int off = 32; off >= 1; off >>= 1)
#pragma unroll
        for (int c = 0; c < 6; ++c)
            acc[c] += __shfl_xor(acc[c], off, 64);
    float logit[6];
#pragma unroll
    for (int c = 0; c < 6; ++c) logit[c] = acc[c] + b[c];
#pragma unroll
    for (int c = 0; c < 6; ++c)
        if (lane == c) logitsOut[(size_t)gw * 6 + c] = logit[c];
    if (lane == 0) {
        float mx = logit[0];
#pragma unroll
        for (int c = 1; c < 6; ++c) mx = fmaxf(mx, logit[c]);
        float se = 0.0f;
#pragma unroll
        for (int c = 0; c < 6; ++c) se += expf(logit[c] - mx);
        float lse = mx + logf(se);
        int yy = y[gw];
        float ly = 0.0f;
#pragma unroll
        for (int c = 0; c < 6; ++c)
            if (yy == c) ly = logit[c];
        atomicAdd(lossOut, (lse - ly) * invN);
    }
}

extern "C" void kernel_launch(void* const* d_in, const int* in_sizes, int n_in,
                              void* d_out, int out_size, void* d_ws, size_t ws_size,
                              hipStream_t stream)
{
    const float* x     = (const float*)d_in[0];
    const int*   eidx  = (const int*)d_in[1];
    const int*   y     = (const int*)d_in[2];
    const float* lin_w = (const float*)d_in[3];
    const float* lin_b = (const float*)d_in[4];
    const float* w1    = (const float*)d_in[5];
    const float* wih1  = (const float*)d_in[6];
    const float* whh1  = (const float*)d_in[7];
    const float* bih1  = (const float*)d_in[8];
    const float* bhh1  = (const float*)d_in[9];
    const float* w2    = (const float*)d_in[10];
    const float* wih2  = (const float*)d_in[11];
    const float* whh2  = (const float*)d_in[12];
    const float* bih2  = (const float*)d_in[13];
    const float* bhh2  = (const float*)d_in[14];
    const float* cls_w = (const float*)d_in[15];
    const float* cls_b = (const float*)d_in[16];

    const int N   = in_sizes[2];
    const int E   = in_sizes[1] / 2;
    const int DIN = in_sizes[0] / N;   // 256
    const int H   = 128;
    const int L   = 6;
    const size_t NH = (size_t)N * H;

    float* out    = (float*)d_out;
    float* logits = out;                         // N*L
    float* loss   = out + (size_t)N * L;         // 1
    float* feats  = out + (size_t)N * L + 1;     // N*H

    float* ws  = (float*)d_ws;
    float* h   = ws;                 // NH
    float* giR = ws + NH;            // 3*NH
    float* ghR = ws + 4 * NH;        // 3*NH
    float* m   = giR;                // overlaps gi region (dead before gi write)
    float* agg = ghR;                // overlaps gh region (dead before gh write)

    const int* src = eidx;
    const int* dst = eidx + E;

    auto gemmGrid = [](int M_, int Nc_) { return dim3((unsigned)(Nc_ / BN), (unsigned)((M_ + BM - 1) / BM)); };
    dim3 blk(256);

    // h = x @ lin_w + lin_b
    sgemm_bias<false><<<gemmGrid(N, H), blk, 0, stream>>>(x, lin_w, lin_b, h, N, H, DIN);

    // ---- GatedGraphConv layer 1 ----
    sgemm_bias<false><<<gemmGrid(N, H), blk, 0, stream>>>(h, w1, nullptr, m, N, H, H);
    hipMemsetAsync(agg, 0, NH * sizeof(float), stream);
    scatter_add_kernel<<<dim3((unsigned)((E + 3) / 4)), blk, 0, stream>>>(m, src, dst, agg, E);
    sgemm_bias<true><<<gemmGrid(N, 3 * H), blk, 0, stream>>>(agg, wih1, bih1, giR, N, 3 * H, H);
    sgemm_bias<true><<<gemmGrid(N, 3 * H), blk, 0, stream>>>(h, whh1, bhh1, ghR, N, 3 * H, H);
    gru_kernel<<<dim3((unsigned)((NH + 255) / 256)), blk, 0, stream>>>(giR, ghR, h, h, (int)NH, 1);

    // ---- GatedGraphConv layer 2 ----
    sgemm_bias<false><<<gemmGrid(N, H), blk, 0, stream>>>(h, w2, nullptr, m, N, H, H);
    hipMemsetAsync(agg, 0, NH * sizeof(float), stream);
    scatter_add_kernel<<<dim3((unsigned)((E + 3) / 4)), blk, 0, stream>>>(m, src, dst, agg, E);
    sgemm_bias<true><<<gemmGrid(N, 3 * H), blk, 0, stream>>>(agg, wih2, bih2, giR, N, 3 * H, H);
    sgemm_bias<true><<<gemmGrid(N, 3 * H), blk, 0, stream>>>(h, whh2, bhh2, ghR, N, 3 * H, H);
    gru_kernel<<<dim3((unsigned)((NH + 255) / 256)), blk, 0, stream>>>(giR, ghR, h, feats, (int)NH, 0);

    // ---- classifier + loss ----
    hipMemsetAsync(loss, 0, sizeof(float), stream);
    cls_kernel<<<dim3((unsigned)((N + 3) / 4)), blk, 0, stream>>>(feats, cls_w, cls_b, y, logits, loss, N, 1.0f / (float)N);
}

// Round 2
// 1563.982 us; speedup vs baseline: 1.6304x; 1.6304x over previous
//
#include <hip/hip_runtime.h>
#include <cstddef>
#include <cstdint>

#define BM 128
#define BN 128
#define BK 16

// C[M,Nc] = A[M,K] @ op(B) + bias ; op(B)=B [K,Nc] (TRANS_B=false) or B^T with B [Nc,K] (TRANS_B=true)
template<bool TRANS_B>
__global__ __launch_bounds__(256)
void sgemm_bias(const float* __restrict__ A, const float* __restrict__ B,
                const float* __restrict__ bias, float* __restrict__ C,
                int M, int Nc, int K)
{
    __shared__ float As[BK][BM + 4];
    __shared__ float Bs[BK][BN + 4];
    const int t  = threadIdx.x;
    const int tx = t & 15, ty = t >> 4;
    const int row0 = blockIdx.y * BM;
    const int col0 = blockIdx.x * BN;

    float acc[8][8];
#pragma unroll
    for (int i = 0; i < 8; ++i)
#pragma unroll
        for (int j = 0; j < 8; ++j) acc[i][j] = 0.0f;

    for (int k0 = 0; k0 < K; k0 += BK) {
#pragma unroll
        for (int qq = 0; qq < 2; ++qq) {
            int q = t + qq * 256;
            int row = q >> 2, kq = q & 3;
            float4 v = make_float4(0.f, 0.f, 0.f, 0.f);
            if (row0 + row < M)
                v = *(const float4*)&A[(size_t)(row0 + row) * K + k0 + kq * 4];
            As[kq * 4 + 0][row] = v.x;
            As[kq * 4 + 1][row] = v.y;
            As[kq * 4 + 2][row] = v.z;
            As[kq * 4 + 3][row] = v.w;
        }
        if (TRANS_B) {
#pragma unroll
            for (int qq = 0; qq < 2; ++qq) {
                int q = t + qq * 256;
                int col = q >> 2, kq = q & 3;
                float4 v = *(const float4*)&B[(size_t)(col0 + col) * K + k0 + kq * 4];
                Bs[kq * 4 + 0][col] = v.x;
                Bs[kq * 4 + 1][col] = v.y;
                Bs[kq * 4 + 2][col] = v.z;
                Bs[kq * 4 + 3][col] = v.w;
            }
        } else {
#pragma unroll
            for (int qq = 0; qq < 2; ++qq) {
                int q = t + qq * 256;
                int kk = q >> 5, nq = q & 31;
                float4 v = *(const float4*)&B[(size_t)(k0 + kk) * Nc + col0 + nq * 4];
                *(float4*)&Bs[kk][nq * 4] = v;
            }
        }
        __syncthreads();
#pragma unroll
        for (int kk = 0; kk < BK; ++kk) {
            float a[8], b[8];
            *(float4*)&a[0] = *(const float4*)&As[kk][ty * 8];
            *(float4*)&a[4] = *(const float4*)&As[kk][ty * 8 + 4];
            *(float4*)&b[0] = *(const float4*)&Bs[kk][tx * 8];
            *(float4*)&b[4] = *(const float4*)&Bs[kk][tx * 8 + 4];
#pragma unroll
            for (int i = 0; i < 8; ++i)
#pragma unroll
                for (int j = 0; j < 8; ++j)
                    acc[i][j] = fmaf(a[i], b[j], acc[i][j]);
        }
        __syncthreads();
    }

#pragma unroll
    for (int i = 0; i < 8; ++i) {
        int r = row0 + ty * 8 + i;
        if (r < M) {
#pragma unroll
            for (int j = 0; j < 8; ++j) {
                int c = col0 + tx * 8 + j;
                float bv = bias ? bias[c] : 0.0f;
                C[(size_t)r * Nc + c] = acc[i][j] + bv;
            }
        }
    }
}

// ---------------- CSR build (counting sort of edges by dst) ----------------

__global__ __launch_bounds__(256)
void hist_kernel(const int* __restrict__ dst, int* __restrict__ deg, int E)
{
    int e = blockIdx.x * 256 + threadIdx.x;
    if (e < E) atomicAdd(&deg[dst[e]], 1);
}

// single-block exclusive scan: off[i] = sum(deg[0..i-1]), off[N] = E
__global__ __launch_bounds__(1024)
void scan_kernel(const int* __restrict__ deg, int* __restrict__ off, int N)
{
    __shared__ int buf[1024];
    __shared__ int carry;
    if (threadIdx.x == 0) carry = 0;
    __syncthreads();
    for (int base = 0; base < N; base += 1024) {
        int i = base + (int)threadIdx.x;
        int v = (i < N) ? deg[i] : 0;
        buf[threadIdx.x] = v;
        __syncthreads();
        for (int o = 1; o < 1024; o <<= 1) {
            int t = (threadIdx.x >= (unsigned)o) ? buf[threadIdx.x - o] : 0;
            __syncthreads();
            buf[threadIdx.x] += t;
            __syncthreads();
        }
        if (i < N) off[i] = carry + buf[threadIdx.x] - v;
        __syncthreads();
        if (threadIdx.x == 1023) carry += buf[1023];
        __syncthreads();
    }
    if (threadIdx.x == 0) off[N] = carry;
}

__global__ __launch_bounds__(256)
void sort_kernel(const int* __restrict__ src, const int* __restrict__ dst,
                 int* __restrict__ cursor, int* __restrict__ ssrc, int E)
{
    int e = blockIdx.x * 256 + threadIdx.x;
    if (e >= E) return;
    int pos = atomicAdd(&cursor[dst[e]], 1);
    ssrc[pos] = src[e];
}

// one wave per dst node: agg[n] = sum over incoming edges of m[ssrc[e]] (no atomics)
__global__ __launch_bounds__(256)
void gather_agg(const float* __restrict__ m, const int* __restrict__ off,
                const int* __restrict__ ssrc, float* __restrict__ agg, int N)
{
    int w = (blockIdx.x * 256 + threadIdx.x) >> 6;
    int lane = threadIdx.x & 63;
    if (w >= N) return;
    int e0 = off[w], e1 = off[w + 1];
    float2 a0 = make_float2(0.f, 0.f), a1 = make_float2(0.f, 0.f);
    int e = e0;
    for (; e + 1 < e1; e += 2) {
        int s0 = ssrc[e], s1 = ssrc[e + 1];
        float2 v0 = *(const float2*)&m[(size_t)s0 * 128 + lane * 2];
        float2 v1 = *(const float2*)&m[(size_t)s1 * 128 + lane * 2];
        a0.x += v0.x; a0.y += v0.y;
        a1.x += v1.x; a1.y += v1.y;
    }
    if (e < e1) {
        int s0 = ssrc[e];
        float2 v0 = *(const float2*)&m[(size_t)s0 * 128 + lane * 2];
        a0.x += v0.x; a0.y += v0.y;
    }
    a0.x += a1.x; a0.y += a1.y;
    *(float2*)&agg[(size_t)w * 128 + lane * 2] = a0;
}

// fallback: one wave per edge with float atomics
__global__ __launch_bounds__(256)
void scatter_add_kernel(const float* __restrict__ m, const int* __restrict__ src,
                        const int* __restrict__ dst, float* __restrict__ agg, int E)
{
    int w = (blockIdx.x * 256 + threadIdx.x) >> 6;
    int lane = threadIdx.x & 63;
    if (w >= E) return;
    int s = src[w], d = dst[w];
    float2 v = *(const float2*)&m[(size_t)s * 128 + lane * 2];
    atomicAdd(&agg[(size_t)d * 128 + lane * 2], v.x);
    atomicAdd(&agg[(size_t)d * 128 + lane * 2 + 1], v.y);
}

// GRUCell elementwise: gi/gh are [N,384], hin [N,128] ; H=128 hard-coded
__global__ __launch_bounds__(256)
void gru_kernel(const float* __restrict__ gi, const float* __restrict__ gh,
                const float* __restrict__ hin, float* __restrict__ hout,
                int NHtot, int applyElu)
{
    int idx = blockIdx.x * 256 + threadIdx.x;
    if (idx >= NHtot) return;
    int n = idx >> 7;
    int j = idx & 127;
    size_t base = (size_t)n * 384 + j;
    float ir = gi[base], iz = gi[base + 128], in_ = gi[base + 256];
    float hr = gh[base], hz = gh[base + 128], hn = gh[base + 256];
    float hv = hin[idx];
    float r = 1.0f / (1.0f + expf(-(ir + hr)));
    float z = 1.0f / (1.0f + expf(-(iz + hz)));
    float nn = tanhf(in_ + r * hn);
    float o = (1.0f - z) * nn + z * hv;
    if (applyElu) o = (o > 0.0f) ? o : expm1f(o);
    hout[idx] = o;
}

// one wave per node: logits = h@W + b ; log_softmax ; loss += (lse - logit[y])/N
__global__ __launch_bounds__(256)
void cls_kernel(const float* __restrict__ h, const float* __restrict__ W,
                const float* __restrict__ b, const int* __restrict__ y,
                float* __restrict__ logitsOut, float* __restrict__ lossOut,
                int N, float invN)
{
    int gw = (blockIdx.x * 256 + threadIdx.x) >> 6;
    int lane = threadIdx.x & 63;
    if (gw >= N) return;
    float h0 = h[(size_t)gw * 128 + lane * 2];
    float h1 = h[(size_t)gw * 128 + lane * 2 + 1];
    float acc[6];
#pragma unroll
    for (int c = 0; c < 6; ++c)
        acc[c] = h0 * W[(lane * 2) * 6 + c] + h1 * W[(lane * 2 + 1) * 6 + c];
#pragma unroll
    for (int off = 32; off >= 1; off >>= 1)
#pragma unroll
        for (int c = 0; c < 6; ++c)
            acc[c] += __shfl_xor(acc[c], off, 64);
    float logit[6];
#pragma unroll
    for (int c = 0; c < 6; ++c) logit[c] = acc[c] + b[c];
#pragma unroll
    for (int c = 0; c < 6; ++c)
        if (lane == c) logitsOut[(size_t)gw * 6 + c] = logit[c];
    if (lane == 0) {
        float mx = logit[0];
#pragma unroll
        for (int c = 1; c < 6; ++c) mx = fmaxf(mx, logit[c]);
        float se = 0.0f;
#pragma unroll
        for (int c = 0; c < 6; ++c) se += expf(logit[c] - mx);
        float lse = mx + logf(se);
        int yy = y[gw];
        float ly = 0.0f;
#pragma unroll
        for (int c = 0; c < 6; ++c)
            if (yy == c) ly = logit[c];
        atomicAdd(lossOut, (lse - ly) * invN);
    }
}

extern "C" void kernel_launch(void* const* d_in, const int* in_sizes, int n_in,
                              void* d_out, int out_size, void* d_ws, size_t ws_size,
                              hipStream_t stream)
{
    const float* x     = (const float*)d_in[0];
    const int*   eidx  = (const int*)d_in[1];
    const int*   y     = (const int*)d_in[2];
    const float* lin_w = (const float*)d_in[3];
    const float* lin_b = (const float*)d_in[4];
    const float* w1    = (const float*)d_in[5];
    const float* wih1  = (const float*)d_in[6];
    const float* whh1  = (const float*)d_in[7];
    const float* bih1  = (const float*)d_in[8];
    const float* bhh1  = (const float*)d_in[9];
    const float* w2    = (const float*)d_in[10];
    const float* wih2  = (const float*)d_in[11];
    const float* whh2  = (const float*)d_in[12];
    const float* bih2  = (const float*)d_in[13];
    const float* bhh2  = (const float*)d_in[14];
    const float* cls_w = (const float*)d_in[15];
    const float* cls_b = (const float*)d_in[16];

    const int N   = in_sizes[2];
    const int E   = in_sizes[1] / 2;
    const int DIN = in_sizes[0] / N;   // 256
    const int H   = 128;
    const int L   = 6;
    const size_t NH = (size_t)N * H;

    float* out    = (float*)d_out;
    float* logits = out;
    float* loss   = out + (size_t)N * L;
    float* feats  = out + (size_t)N * L + 1;

    float* ws  = (float*)d_ws;
    float* h   = ws;                 // NH
    float* giR = ws + NH;            // 3*NH
    float* ghR = ws + 4 * NH;        // 3*NH
    float* m   = giR;                // overlaps gi region (dead before gi write)
    float* agg = ghR;                // overlaps gh region (dead before gh write)

    // CSR-by-dst arrays in ws tail (built once, reused by both layers)
    int* off    = (int*)(ws + 7 * NH);   // N+1
    int* cursor = off + (N + 1);         // N
    int* ssrc   = cursor + N;            // E
    size_t need = 7 * NH * sizeof(float) + (size_t)(2 * N + 1 + E) * sizeof(int);
    bool useSorted = (ws_size >= need);

    const int* src = eidx;
    const int* dst = eidx + E;

    auto gemmGrid = [](int M_, int Nc_) { return dim3((unsigned)(Nc_ / BN), (unsigned)((M_ + BM - 1) / BM)); };
    dim3 blk(256);
    unsigned egrid = (unsigned)((E + 255) / 256);
    unsigned ngridW = (unsigned)((N + 3) / 4);   // wave-per-node grids

    if (useSorted) {
        hipMemsetAsync(cursor, 0, (size_t)N * sizeof(int), stream);
        hist_kernel<<<dim3(egrid), blk, 0, stream>>>(dst, cursor, E);
        scan_kernel<<<dim3(1), dim3(1024), 0, stream>>>(cursor, off, N);
        hipMemcpyAsync(cursor, off, (size_t)N * sizeof(int), hipMemcpyDeviceToDevice, stream);
        sort_kernel<<<dim3(egrid), blk, 0, stream>>>(src, dst, cursor, ssrc, E);
    }

    // h = x @ lin_w + lin_b
    sgemm_bias<false><<<gemmGrid(N, H), blk, 0, stream>>>(x, lin_w, lin_b, h, N, H, DIN);

    // ---- GatedGraphConv layer 1 ----
    sgemm_bias<false><<<gemmGrid(N, H), blk, 0, stream>>>(h, w1, nullptr, m, N, H, H);
    if (useSorted) {
        gather_agg<<<dim3(ngridW), blk, 0, stream>>>(m, off, ssrc, agg, N);
    } else {
        hipMemsetAsync(agg, 0, NH * sizeof(float), stream);
        scatter_add_kernel<<<dim3((unsigned)((E + 3) / 4)), blk, 0, stream>>>(m, src, dst, agg, E);
    }
    sgemm_bias<true><<<gemmGrid(N, 3 * H), blk, 0, stream>>>(agg, wih1, bih1, giR, N, 3 * H, H);
    sgemm_bias<true><<<gemmGrid(N, 3 * H), blk, 0, stream>>>(h, whh1, bhh1, ghR, N, 3 * H, H);
    gru_kernel<<<dim3((unsigned)((NH + 255) / 256)), blk, 0, stream>>>(giR, ghR, h, h, (int)NH, 1);

    // ---- GatedGraphConv layer 2 ----
    sgemm_bias<false><<<gemmGrid(N, H), blk, 0, stream>>>(h, w2, nullptr, m, N, H, H);
    if (useSorted) {
        gather_agg<<<dim3(ngridW), blk, 0, stream>>>(m, off, ssrc, agg, N);
    } else {
        hipMemsetAsync(agg, 0, NH * sizeof(float), stream);
        scatter_add_kernel<<<dim3((unsigned)((E + 3) / 4)), blk, 0, stream>>>(m, src, dst, agg, E);
    }
    sgemm_bias<true><<<gemmGrid(N, 3 * H), blk, 0, stream>>>(agg, wih2, bih2, giR, N, 3 * H, H);
    sgemm_bias<true><<<gemmGrid(N, 3 * H), blk, 0, stream>>>(h, whh2, bhh2, ghR, N, 3 * H, H);
    gru_kernel<<<dim3((unsigned)((NH + 255) / 256)), blk, 0, stream>>>(giR, ghR, h, feats, (int)NH, 0);

    // ---- classifier + loss ----
    hipMemsetAsync(loss, 0, sizeof(float), stream);
    cls_kernel<<<dim3(ngridW), blk, 0, stream>>>(feats, cls_w, cls_b, y, logits, loss, N, 1.0f / (float)N);
}

// Round 3
// 947.596 us; speedup vs baseline: 2.6909x; 1.6505x over previous
//
#include <hip/hip_runtime.h>
#include <cstddef>
#include <cstdint>

#define BM 128
#define BN 128
#define BK 16

// C[M,Nc] = A[M,K] @ op(B) + bias ; op(B)=B [K,Nc] (TRANS_B=false) or B^T with B [Nc,K] (TRANS_B=true)
template<bool TRANS_B>
__global__ __launch_bounds__(256)
void sgemm_bias(const float* __restrict__ A, const float* __restrict__ B,
                const float* __restrict__ bias, float* __restrict__ C,
                int M, int Nc, int K)
{
    __shared__ float As[BK][BM + 4];
    __shared__ float Bs[BK][BN + 4];
    const int t  = threadIdx.x;
    const int tx = t & 15, ty = t >> 4;
    const int row0 = blockIdx.y * BM;
    const int col0 = blockIdx.x * BN;

    float acc[8][8];
#pragma unroll
    for (int i = 0; i < 8; ++i)
#pragma unroll
        for (int j = 0; j < 8; ++j) acc[i][j] = 0.0f;

    for (int k0 = 0; k0 < K; k0 += BK) {
#pragma unroll
        for (int qq = 0; qq < 2; ++qq) {
            int q = t + qq * 256;
            int row = q >> 2, kq = q & 3;
            float4 v = make_float4(0.f, 0.f, 0.f, 0.f);
            if (row0 + row < M)
                v = *(const float4*)&A[(size_t)(row0 + row) * K + k0 + kq * 4];
            As[kq * 4 + 0][row] = v.x;
            As[kq * 4 + 1][row] = v.y;
            As[kq * 4 + 2][row] = v.z;
            As[kq * 4 + 3][row] = v.w;
        }
        if (TRANS_B) {
#pragma unroll
            for (int qq = 0; qq < 2; ++qq) {
                int q = t + qq * 256;
                int col = q >> 2, kq = q & 3;
                float4 v = *(const float4*)&B[(size_t)(col0 + col) * K + k0 + kq * 4];
                Bs[kq * 4 + 0][col] = v.x;
                Bs[kq * 4 + 1][col] = v.y;
                Bs[kq * 4 + 2][col] = v.z;
                Bs[kq * 4 + 3][col] = v.w;
            }
        } else {
#pragma unroll
            for (int qq = 0; qq < 2; ++qq) {
                int q = t + qq * 256;
                int kk = q >> 5, nq = q & 31;
                float4 v = *(const float4*)&B[(size_t)(k0 + kk) * Nc + col0 + nq * 4];
                *(float4*)&Bs[kk][nq * 4] = v;
            }
        }
        __syncthreads();
#pragma unroll
        for (int kk = 0; kk < BK; ++kk) {
            float a[8], b[8];
            *(float4*)&a[0] = *(const float4*)&As[kk][ty * 8];
            *(float4*)&a[4] = *(const float4*)&As[kk][ty * 8 + 4];
            *(float4*)&b[0] = *(const float4*)&Bs[kk][tx * 8];
            *(float4*)&b[4] = *(const float4*)&Bs[kk][tx * 8 + 4];
#pragma unroll
            for (int i = 0; i < 8; ++i)
#pragma unroll
                for (int j = 0; j < 8; ++j)
                    acc[i][j] = fmaf(a[i], b[j], acc[i][j]);
        }
        __syncthreads();
    }

#pragma unroll
    for (int i = 0; i < 8; ++i) {
        int r = row0 + ty * 8 + i;
        if (r < M) {
#pragma unroll
            for (int j = 0; j < 8; ++j) {
                int c = col0 + tx * 8 + j;
                float bv = bias ? bias[c] : 0.0f;
                C[(size_t)r * Nc + c] = acc[i][j] + bv;
            }
        }
    }
}

// ---------------- CSR build (counting sort of edges by dst) ----------------

__global__ __launch_bounds__(256)
void hist_kernel(const int* __restrict__ dst, int* __restrict__ deg, int E)
{
    int e = blockIdx.x * 256 + threadIdx.x;
    if (e < E) atomicAdd(&deg[dst[e]], 1);
}

// single-block exclusive scan: off[i] = sum(deg[0..i-1]), off[N] = E
__global__ __launch_bounds__(1024)
void scan_kernel(const int* __restrict__ deg, int* __restrict__ off, int N)
{
    __shared__ int buf[1024];
    __shared__ int carry;
    if (threadIdx.x == 0) carry = 0;
    __syncthreads();
    for (int base = 0; base < N; base += 1024) {
        int i = base + (int)threadIdx.x;
        int v = (i < N) ? deg[i] : 0;
        buf[threadIdx.x] = v;
        __syncthreads();
        for (int o = 1; o < 1024; o <<= 1) {
            int t = (threadIdx.x >= (unsigned)o) ? buf[threadIdx.x - o] : 0;
            __syncthreads();
            buf[threadIdx.x] += t;
            __syncthreads();
        }
        if (i < N) off[i] = carry + buf[threadIdx.x] - v;
        __syncthreads();
        if (threadIdx.x == 1023) carry += buf[1023];
        __syncthreads();
    }
    if (threadIdx.x == 0) off[N] = carry;
}

__global__ __launch_bounds__(256)
void sort_kernel(const int* __restrict__ src, const int* __restrict__ dst,
                 int* __restrict__ cursor, int* __restrict__ ssrc, int E)
{
    int e = blockIdx.x * 256 + threadIdx.x;
    if (e >= E) return;
    int pos = atomicAdd(&cursor[dst[e]], 1);
    ssrc[pos] = src[e];
}

// one wave per dst node: agg[n] = sum over incoming edges of m[ssrc[e]] (no atomics)
__global__ __launch_bounds__(256)
void gather_agg(const float* __restrict__ m, const int* __restrict__ off,
                const int* __restrict__ ssrc, float* __restrict__ agg, int N)
{
    int w = (blockIdx.x * 256 + threadIdx.x) >> 6;
    int lane = threadIdx.x & 63;
    if (w >= N) return;
    int e0 = off[w], e1 = off[w + 1];
    float2 a0 = make_float2(0.f, 0.f), a1 = make_float2(0.f, 0.f);
    int e = e0;
    for (; e + 1 < e1; e += 2) {
        int s0 = ssrc[e], s1 = ssrc[e + 1];
        float2 v0 = *(const float2*)&m[(size_t)s0 * 128 + lane * 2];
        float2 v1 = *(const float2*)&m[(size_t)s1 * 128 + lane * 2];
        a0.x += v0.x; a0.y += v0.y;
        a1.x += v1.x; a1.y += v1.y;
    }
    if (e < e1) {
        int s0 = ssrc[e];
        float2 v0 = *(const float2*)&m[(size_t)s0 * 128 + lane * 2];
        a0.x += v0.x; a0.y += v0.y;
    }
    a0.x += a1.x; a0.y += a1.y;
    *(float2*)&agg[(size_t)w * 128 + lane * 2] = a0;
}

// fallback: one wave per edge with float atomics
__global__ __launch_bounds__(256)
void scatter_add_kernel(const float* __restrict__ m, const int* __restrict__ src,
                        const int* __restrict__ dst, float* __restrict__ agg, int E)
{
    int w = (blockIdx.x * 256 + threadIdx.x) >> 6;
    int lane = threadIdx.x & 63;
    if (w >= E) return;
    int s = src[w], d = dst[w];
    float2 v = *(const float2*)&m[(size_t)s * 128 + lane * 2];
    atomicAdd(&agg[(size_t)d * 128 + lane * 2], v.x);
    atomicAdd(&agg[(size_t)d * 128 + lane * 2 + 1], v.y);
}

// GRUCell elementwise: gi/gh are [N,384], hin [N,128] ; H=128 hard-coded
__global__ __launch_bounds__(256)
void gru_kernel(const float* __restrict__ gi, const float* __restrict__ gh,
                const float* __restrict__ hin, float* __restrict__ hout,
                int NHtot, int applyElu)
{
    int idx = blockIdx.x * 256 + threadIdx.x;
    if (idx >= NHtot) return;
    int n = idx >> 7;
    int j = idx & 127;
    size_t base = (size_t)n * 384 + j;
    float ir = gi[base], iz = gi[base + 128], in_ = gi[base + 256];
    float hr = gh[base], hz = gh[base + 128], hn = gh[base + 256];
    float hv = hin[idx];
    float r = 1.0f / (1.0f + expf(-(ir + hr)));
    float z = 1.0f / (1.0f + expf(-(iz + hz)));
    float nn = tanhf(in_ + r * hn);
    float o = (1.0f - z) * nn + z * hv;
    if (applyElu) o = (o > 0.0f) ? o : expm1f(o);
    hout[idx] = o;
}

// one wave per node: logits = h@W + b ; log_softmax ; per-block partial loss (no global atomics)
__global__ __launch_bounds__(256)
void cls_kernel(const float* __restrict__ h, const float* __restrict__ W,
                const float* __restrict__ b, const int* __restrict__ y,
                float* __restrict__ logitsOut, float* __restrict__ partials,
                int N, float invN)
{
    __shared__ float pl[4];
    const int wid  = threadIdx.x >> 6;
    const int lane = threadIdx.x & 63;
    const int gw   = blockIdx.x * 4 + wid;
    if (threadIdx.x < 4) pl[threadIdx.x] = 0.0f;
    __syncthreads();
    if (gw < N) {
        float h0 = h[(size_t)gw * 128 + lane * 2];
        float h1 = h[(size_t)gw * 128 + lane * 2 + 1];
        float acc[6];
#pragma unroll
        for (int c = 0; c < 6; ++c)
            acc[c] = h0 * W[(lane * 2) * 6 + c] + h1 * W[(lane * 2 + 1) * 6 + c];
#pragma unroll
        for (int off = 32; off >= 1; off >>= 1)
#pragma unroll
            for (int c = 0; c < 6; ++c)
                acc[c] += __shfl_xor(acc[c], off, 64);
        float logit[6];
#pragma unroll
        for (int c = 0; c < 6; ++c) logit[c] = acc[c] + b[c];
#pragma unroll
        for (int c = 0; c < 6; ++c)
            if (lane == c) logitsOut[(size_t)gw * 6 + c] = logit[c];
        if (lane == 0) {
            float mx = logit[0];
#pragma unroll
            for (int c = 1; c < 6; ++c) mx = fmaxf(mx, logit[c]);
            float se = 0.0f;
#pragma unroll
            for (int c = 0; c < 6; ++c) se += expf(logit[c] - mx);
            float lse = mx + logf(se);
            int yy = y[gw];
            float ly = 0.0f;
#pragma unroll
            for (int c = 0; c < 6; ++c)
                if (yy == c) ly = logit[c];
            pl[wid] = (lse - ly) * invN;
        }
    }
    __syncthreads();
    if (threadIdx.x == 0)
        partials[blockIdx.x] = pl[0] + pl[1] + pl[2] + pl[3];
}

__global__ __launch_bounds__(1024)
void loss_reduce(const float* __restrict__ partials, float* __restrict__ loss, int P)
{
    __shared__ float buf[1024];
    float s = 0.0f;
    for (int i = threadIdx.x; i < (unsigned)P; i += 1024) s += partials[i];
    buf[threadIdx.x] = s;
    __syncthreads();
    for (int o = 512; o >= 1; o >>= 1) {
        if (threadIdx.x < (unsigned)o) buf[threadIdx.x] += buf[threadIdx.x + o];
        __syncthreads();
    }
    if (threadIdx.x == 0) loss[0] = buf[0];
}

extern "C" void kernel_launch(void* const* d_in, const int* in_sizes, int n_in,
                              void* d_out, int out_size, void* d_ws, size_t ws_size,
                              hipStream_t stream)
{
    const float* x     = (const float*)d_in[0];
    const int*   eidx  = (const int*)d_in[1];
    const int*   y     = (const int*)d_in[2];
    const float* lin_w = (const float*)d_in[3];
    const float* lin_b = (const float*)d_in[4];
    const float* w1    = (const float*)d_in[5];
    const float* wih1  = (const float*)d_in[6];
    const float* whh1  = (const float*)d_in[7];
    const float* bih1  = (const float*)d_in[8];
    const float* bhh1  = (const float*)d_in[9];
    const float* w2    = (const float*)d_in[10];
    const float* wih2  = (const float*)d_in[11];
    const float* whh2  = (const float*)d_in[12];
    const float* bih2  = (const float*)d_in[13];
    const float* bhh2  = (const float*)d_in[14];
    const float* cls_w = (const float*)d_in[15];
    const float* cls_b = (const float*)d_in[16];

    const int N   = in_sizes[2];
    const int E   = in_sizes[1] / 2;
    const int DIN = in_sizes[0] / N;   // 256
    const int H   = 128;
    const int L   = 6;
    const size_t NH = (size_t)N * H;
    const int P   = (N + 3) / 4;       // cls partials (one per block)

    float* out    = (float*)d_out;
    float* logits = out;
    float* loss   = out + (size_t)N * L;
    float* feats  = out + (size_t)N * L + 1;

    float* ws   = (float*)d_ws;
    float* h    = ws;                 // NH
    float* giR  = ws + NH;            // 3*NH
    float* ghR  = ws + 4 * NH;        // 3*NH
    float* m    = giR;                // overlaps gi region (dead before gi write)
    float* agg  = ghR;                // overlaps gh region (dead before gh write)
    float* part = ws + 7 * NH;        // P floats

    // CSR-by-dst arrays in ws tail (built once, reused by both layers)
    int* off    = (int*)(part + P);      // N+1
    int* cursor = off + (N + 1);         // N
    int* ssrc   = cursor + N;            // E
    size_t need = (7 * NH + P) * sizeof(float) + (size_t)(2 * N + 1 + E) * sizeof(int);
    bool useSorted = (ws_size >= need);

    const int* src = eidx;
    const int* dst = eidx + E;

    auto gemmGrid = [](int M_, int Nc_) { return dim3((unsigned)(Nc_ / BN), (unsigned)((M_ + BM - 1) / BM)); };
    dim3 blk(256);
    unsigned egrid = (unsigned)((E + 255) / 256);
    unsigned ngridW = (unsigned)((N + 3) / 4);   // wave-per-node grids

    if (useSorted) {
        hipMemsetAsync(cursor, 0, (size_t)N * sizeof(int), stream);
        hist_kernel<<<dim3(egrid), blk, 0, stream>>>(dst, cursor, E);
        scan_kernel<<<dim3(1), dim3(1024), 0, stream>>>(cursor, off, N);
        hipMemcpyAsync(cursor, off, (size_t)N * sizeof(int), hipMemcpyDeviceToDevice, stream);
        sort_kernel<<<dim3(egrid), blk, 0, stream>>>(src, dst, cursor, ssrc, E);
    }

    // h = x @ lin_w + lin_b
    sgemm_bias<false><<<gemmGrid(N, H), blk, 0, stream>>>(x, lin_w, lin_b, h, N, H, DIN);

    // ---- GatedGraphConv layer 1 ----
    sgemm_bias<false><<<gemmGrid(N, H), blk, 0, stream>>>(h, w1, nullptr, m, N, H, H);
    if (useSorted) {
        gather_agg<<<dim3(ngridW), blk, 0, stream>>>(m, off, ssrc, agg, N);
    } else {
        hipMemsetAsync(agg, 0, NH * sizeof(float), stream);
        scatter_add_kernel<<<dim3((unsigned)((E + 3) / 4)), blk, 0, stream>>>(m, src, dst, agg, E);
    }
    sgemm_bias<true><<<gemmGrid(N, 3 * H), blk, 0, stream>>>(agg, wih1, bih1, giR, N, 3 * H, H);
    sgemm_bias<true><<<gemmGrid(N, 3 * H), blk, 0, stream>>>(h, whh1, bhh1, ghR, N, 3 * H, H);
    gru_kernel<<<dim3((unsigned)((NH + 255) / 256)), blk, 0, stream>>>(giR, ghR, h, h, (int)NH, 1);

    // ---- GatedGraphConv layer 2 ----
    sgemm_bias<false><<<gemmGrid(N, H), blk, 0, stream>>>(h, w2, nullptr, m, N, H, H);
    if (useSorted) {
        gather_agg<<<dim3(ngridW), blk, 0, stream>>>(m, off, ssrc, agg, N);
    } else {
        hipMemsetAsync(agg, 0, NH * sizeof(float), stream);
        scatter_add_kernel<<<dim3((unsigned)((E + 3) / 4)), blk, 0, stream>>>(m, src, dst, agg, E);
    }
    sgemm_bias<true><<<gemmGrid(N, 3 * H), blk, 0, stream>>>(agg, wih2, bih2, giR, N, 3 * H, H);
    sgemm_bias<true><<<gemmGrid(N, 3 * H), blk, 0, stream>>>(h, whh2, bhh2, ghR, N, 3 * H, H);
    gru_kernel<<<dim3((unsigned)((NH + 255) / 256)), blk, 0, stream>>>(giR, ghR, h, feats, (int)NH, 0);

    // ---- classifier + loss (two-stage reduction, no global atomics) ----
    cls_kernel<<<dim3(ngridW), blk, 0, stream>>>(feats, cls_w, cls_b, y, logits, part, N, 1.0f / (float)N);
    loss_reduce<<<dim3(1), dim3(1024), 0, stream>>>(part, loss, P);
}

// Round 4
// 537.633 us; speedup vs baseline: 4.7429x; 1.7625x over previous
//
#include <hip/hip_runtime.h>
#include <cstddef>
#include <cstdint>

typedef __attribute__((ext_vector_type(8))) short bf16x8;
typedef __attribute__((ext_vector_type(4))) float f32x4;
typedef __attribute__((ext_vector_type(8))) unsigned short u16x8;

__device__ inline unsigned short f2bf(float f) {
    unsigned u = __builtin_bit_cast(unsigned, f);
    u += 0x7FFF + ((u >> 16) & 1);          // round-to-nearest-even
    return (unsigned short)(u >> 16);
}

// ---------------- weight prepack: P[kc][c][kk] = Bop[k=kc*32+kk][c] ----------------
// trans=0: S is [K][C] (Bop = S). trans=1: S is [C][K] (Bop[k][c] = S[c][k]).
__global__ __launch_bounds__(256)
void prepack_kernel(const float* __restrict__ S, unsigned short* __restrict__ P,
                    int K, int C, int trans)
{
    int idx = blockIdx.x * 256 + threadIdx.x;
    if (idx >= K * C) return;
    int kk = idx & 31;
    int c  = (idx >> 5) % C;
    int kc = idx / (32 * C);
    int k  = kc * 32 + kk;
    float v = trans ? S[(size_t)c * K + k] : S[(size_t)k * C + c];
    P[idx] = f2bf(v);
}

// ---------------- MFMA GEMM: C[M,128] = A[M,K] @ W (+bias), W pre-packed bf16 ----------------
// block 256 = 4 waves; BM=64; wave (wr,wc): rows wr*32..+31, cols wc*64..+63
__global__ __launch_bounds__(256)
void mfma_xw(const float* __restrict__ A, const unsigned short* __restrict__ P,
             const float* __restrict__ bias, float* __restrict__ C, int M, int K)
{
    __shared__ unsigned short Ab[64 * 32];
    __shared__ unsigned short Bb[128 * 32];
    const int tid  = threadIdx.x;
    const int l    = tid & 63;
    const int w    = tid >> 6;
    const int wr   = w >> 1, wc = w & 1;
    const int row0 = blockIdx.x * 64;

    f32x4 acc[2][4];
#pragma unroll
    for (int i = 0; i < 2; ++i)
#pragma unroll
        for (int j = 0; j < 4; ++j) acc[i][j] = (f32x4){0.f, 0.f, 0.f, 0.f};

    const int KC = K >> 5;
    for (int kc = 0; kc < KC; ++kc) {
        // stage A: 64 rows x 32 k, f32 -> bf16
        {
            int row = tid >> 2, kpos = (tid & 3) * 8;
            unsigned short u[8];
            if (row0 + row < M) {
                const float* src = &A[(size_t)(row0 + row) * K + kc * 32 + kpos];
                float4 v0 = *(const float4*)src;
                float4 v1 = *(const float4*)(src + 4);
                u[0]=f2bf(v0.x); u[1]=f2bf(v0.y); u[2]=f2bf(v0.z); u[3]=f2bf(v0.w);
                u[4]=f2bf(v1.x); u[5]=f2bf(v1.y); u[6]=f2bf(v1.z); u[7]=f2bf(v1.w);
            } else {
#pragma unroll
                for (int q = 0; q < 8; ++q) u[q] = 0;
            }
            *(u16x8*)&Ab[row * 32 + kpos] = *(u16x8*)u;
        }
        // stage B: copy packed chunk (128x32 bf16)
        {
            const u16x8* src = (const u16x8*)(P + (size_t)kc * 4096);
            u16x8* dstL = (u16x8*)Bb;
            dstL[tid * 2]     = src[tid * 2];
            dstL[tid * 2 + 1] = src[tid * 2 + 1];
        }
        __syncthreads();
        bf16x8 af[2], bf[4];
#pragma unroll
        for (int rt = 0; rt < 2; ++rt)
            af[rt] = *(const bf16x8*)&Ab[(wr * 32 + rt * 16 + (l & 15)) * 32 + (l >> 4) * 8];
#pragma unroll
        for (int ct = 0; ct < 4; ++ct)
            bf[ct] = *(const bf16x8*)&Bb[(wc * 64 + ct * 16 + (l & 15)) * 32 + (l >> 4) * 8];
#pragma unroll
        for (int rt = 0; rt < 2; ++rt)
#pragma unroll
            for (int ct = 0; ct < 4; ++ct)
                acc[rt][ct] = __builtin_amdgcn_mfma_f32_16x16x32_bf16(af[rt], bf[ct], acc[rt][ct], 0, 0, 0);
        __syncthreads();
    }

#pragma unroll
    for (int rt = 0; rt < 2; ++rt)
#pragma unroll
        for (int ct = 0; ct < 4; ++ct) {
            int col = wc * 64 + ct * 16 + (l & 15);
            float bv = bias ? bias[col] : 0.0f;
#pragma unroll
            for (int j = 0; j < 4; ++j) {
                int row = row0 + wr * 32 + rt * 16 + (l >> 4) * 4 + j;
                if (row < M) C[(size_t)row * 128 + col] = acc[rt][ct][j] + bv;
            }
        }
}

// ---------------- fused gi/gh GEMMs + GRU ----------------
// block 256 = 4 waves; 32 rows; wave w: output cols w*32..+31
// gi = agg @ wih^T + bih ; gh = h @ whh^T + bhh ; GRU -> hout (optional ELU)
template<int ELU>
__global__ __launch_bounds__(256)
void mfma_gru(const float* __restrict__ agg, const float* __restrict__ hin,
              const unsigned short* __restrict__ wihP, const unsigned short* __restrict__ whhP,
              const float* __restrict__ bih, const float* __restrict__ bhh,
              float* __restrict__ hout, int M)
{
    __shared__ unsigned short Aa[32 * 32];
    __shared__ unsigned short Ah[32 * 32];
    __shared__ unsigned short Bw[384 * 32];
    __shared__ unsigned short Bu[384 * 32];
    const int tid = threadIdx.x;
    const int l   = tid & 63;
    const int w   = tid >> 6;
    const int row0 = blockIdx.x * 32;

    f32x4 gi[3][2][2], gh[3][2][2];   // [group][coltile][rowtile]
#pragma unroll
    for (int g = 0; g < 3; ++g)
#pragma unroll
        for (int ct = 0; ct < 2; ++ct)
#pragma unroll
            for (int rt = 0; rt < 2; ++rt) {
                gi[g][ct][rt] = (f32x4){0.f, 0.f, 0.f, 0.f};
                gh[g][ct][rt] = (f32x4){0.f, 0.f, 0.f, 0.f};
            }

    for (int kc = 0; kc < 4; ++kc) {
        // stage A (agg for tid<128, h for tid>=128): 32 rows x 32 k each
        {
            int t2 = tid & 127;
            int row = t2 >> 2, kpos = (t2 & 3) * 8;
            const float* srcM = (tid < 128) ? agg : hin;
            unsigned short* dstL = (tid < 128) ? Aa : Ah;
            unsigned short u[8];
            if (row0 + row < M) {
                const float* src = &srcM[(size_t)(row0 + row) * 128 + kc * 32 + kpos];
                float4 v0 = *(const float4*)src;
                float4 v1 = *(const float4*)(src + 4);
                u[0]=f2bf(v0.x); u[1]=f2bf(v0.y); u[2]=f2bf(v0.z); u[3]=f2bf(v0.w);
                u[4]=f2bf(v1.x); u[5]=f2bf(v1.y); u[6]=f2bf(v1.z); u[7]=f2bf(v1.w);
            } else {
#pragma unroll
                for (int q = 0; q < 8; ++q) u[q] = 0;
            }
            *(u16x8*)&dstL[row * 32 + kpos] = *(u16x8*)u;
        }
        // stage B: two packed chunks (384x32 bf16 each = 1536 u16x8 units)
        {
            const u16x8* sw = (const u16x8*)(wihP + (size_t)kc * 12288);
            const u16x8* su = (const u16x8*)(whhP + (size_t)kc * 12288);
            u16x8* dw = (u16x8*)Bw;
            u16x8* du = (u16x8*)Bu;
#pragma unroll
            for (int q = 0; q < 6; ++q) {
                int u = tid + q * 256;
                dw[u] = sw[u];
                du[u] = su[u];
            }
        }
        __syncthreads();

        bf16x8 aa[2], ah[2];
#pragma unroll
        for (int rt = 0; rt < 2; ++rt) {
            int off = (rt * 16 + (l & 15)) * 32 + (l >> 4) * 8;
            aa[rt] = *(const bf16x8*)&Aa[off];
            ah[rt] = *(const bf16x8*)&Ah[off];
        }
#pragma unroll
        for (int g = 0; g < 3; ++g)
#pragma unroll
            for (int ct = 0; ct < 2; ++ct) {
                int cgi = g * 128 + w * 32 + ct * 16 + (l & 15);
                int off = cgi * 32 + (l >> 4) * 8;
                bf16x8 bw = *(const bf16x8*)&Bw[off];
                bf16x8 bu = *(const bf16x8*)&Bu[off];
#pragma unroll
                for (int rt = 0; rt < 2; ++rt) {
                    gi[g][ct][rt] = __builtin_amdgcn_mfma_f32_16x16x32_bf16(aa[rt], bw, gi[g][ct][rt], 0, 0, 0);
                    gh[g][ct][rt] = __builtin_amdgcn_mfma_f32_16x16x32_bf16(ah[rt], bu, gh[g][ct][rt], 0, 0, 0);
                }
            }
        __syncthreads();
    }

    // GRU epilogue
#pragma unroll
    for (int ct = 0; ct < 2; ++ct) {
        int col = w * 32 + ct * 16 + (l & 15);
        float bir = bih[col], biz = bih[128 + col], bin = bih[256 + col];
        float bhr = bhh[col], bhz = bhh[128 + col], bhn = bhh[256 + col];
#pragma unroll
        for (int rt = 0; rt < 2; ++rt)
#pragma unroll
            for (int j = 0; j < 4; ++j) {
                int row = row0 + rt * 16 + (l >> 4) * 4 + j;
                if (row >= M) continue;
                float ir = gi[0][ct][rt][j] + bir;
                float iz = gi[1][ct][rt][j] + biz;
                float in_ = gi[2][ct][rt][j] + bin;
                float hr = gh[0][ct][rt][j] + bhr;
                float hz = gh[1][ct][rt][j] + bhz;
                float hn = gh[2][ct][rt][j] + bhn;
                float hv = hin[(size_t)row * 128 + col];
                float r = 1.0f / (1.0f + expf(-(ir + hr)));
                float z = 1.0f / (1.0f + expf(-(iz + hz)));
                float nn = tanhf(in_ + r * hn);
                float o = (1.0f - z) * nn + z * hv;
                if (ELU) o = (o > 0.0f) ? o : expm1f(o);
                hout[(size_t)row * 128 + col] = o;
            }
    }
}

// ---------------- CSR build (counting sort of edges by dst) ----------------

__global__ __launch_bounds__(256)
void hist_kernel(const int* __restrict__ dst, int* __restrict__ deg, int E)
{
    int e = blockIdx.x * 256 + threadIdx.x;
    if (e < E) atomicAdd(&deg[dst[e]], 1);
}

__global__ __launch_bounds__(1024)
void scan_kernel(const int* __restrict__ deg, int* __restrict__ off, int N)
{
    __shared__ int buf[1024];
    __shared__ int carry;
    if (threadIdx.x == 0) carry = 0;
    __syncthreads();
    for (int base = 0; base < N; base += 1024) {
        int i = base + (int)threadIdx.x;
        int v = (i < N) ? deg[i] : 0;
        buf[threadIdx.x] = v;
        __syncthreads();
        for (int o = 1; o < 1024; o <<= 1) {
            int t = (threadIdx.x >= (unsigned)o) ? buf[threadIdx.x - o] : 0;
            __syncthreads();
            buf[threadIdx.x] += t;
            __syncthreads();
        }
        if (i < N) off[i] = carry + buf[threadIdx.x] - v;
        __syncthreads();
        if (threadIdx.x == 1023) carry += buf[1023];
        __syncthreads();
    }
    if (threadIdx.x == 0) off[N] = carry;
}

__global__ __launch_bounds__(256)
void sort_kernel(const int* __restrict__ src, const int* __restrict__ dst,
                 int* __restrict__ cursor, int* __restrict__ ssrc, int E)
{
    int e = blockIdx.x * 256 + threadIdx.x;
    if (e >= E) return;
    int pos = atomicAdd(&cursor[dst[e]], 1);
    ssrc[pos] = src[e];
}

// one wave per dst node: agg[n] = sum over incoming edges of m[ssrc[e]]
__global__ __launch_bounds__(256)
void gather_agg(const float* __restrict__ m, const int* __restrict__ off,
                const int* __restrict__ ssrc, float* __restrict__ agg, int N)
{
    int w = (blockIdx.x * 256 + threadIdx.x) >> 6;
    int lane = threadIdx.x & 63;
    if (w >= N) return;
    int e0 = off[w], e1 = off[w + 1];
    float2 a0 = make_float2(0.f, 0.f), a1 = make_float2(0.f, 0.f);
    int e = e0;
    for (; e + 1 < e1; e += 2) {
        int s0 = ssrc[e], s1 = ssrc[e + 1];
        float2 v0 = *(const float2*)&m[(size_t)s0 * 128 + lane * 2];
        float2 v1 = *(const float2*)&m[(size_t)s1 * 128 + lane * 2];
        a0.x += v0.x; a0.y += v0.y;
        a1.x += v1.x; a1.y += v1.y;
    }
    if (e < e1) {
        int s0 = ssrc[e];
        float2 v0 = *(const float2*)&m[(size_t)s0 * 128 + lane * 2];
        a0.x += v0.x; a0.y += v0.y;
    }
    a0.x += a1.x; a0.y += a1.y;
    *(float2*)&agg[(size_t)w * 128 + lane * 2] = a0;
}

// one wave per node: logits = h@W + b ; log_softmax ; per-block partial loss
__global__ __launch_bounds__(256)
void cls_kernel(const float* __restrict__ h, const float* __restrict__ W,
                const float* __restrict__ b, const int* __restrict__ y,
                float* __restrict__ logitsOut, float* __restrict__ partials,
                int N, float invN)
{
    __shared__ float pl[4];
    const int wid  = threadIdx.x >> 6;
    const int lane = threadIdx.x & 63;
    const int gw   = blockIdx.x * 4 + wid;
    if (threadIdx.x < 4) pl[threadIdx.x] = 0.0f;
    __syncthreads();
    if (gw < N) {
        float h0 = h[(size_t)gw * 128 + lane * 2];
        float h1 = h[(size_t)gw * 128 + lane * 2 + 1];
        float acc[6];
#pragma unroll
        for (int c = 0; c < 6; ++c)
            acc[c] = h0 * W[(lane * 2) * 6 + c] + h1 * W[(lane * 2 + 1) * 6 + c];
#pragma unroll
        for (int off = 32; off >= 1; off >>= 1)
#pragma unroll
            for (int c = 0; c < 6; ++c)
                acc[c] += __shfl_xor(acc[c], off, 64);
        float logit[6];
#pragma unroll
        for (int c = 0; c < 6; ++c) logit[c] = acc[c] + b[c];
#pragma unroll
        for (int c = 0; c < 6; ++c)
            if (lane == c) logitsOut[(size_t)gw * 6 + c] = logit[c];
        if (lane == 0) {
            float mx = logit[0];
#pragma unroll
            for (int c = 1; c < 6; ++c) mx = fmaxf(mx, logit[c]);
            float se = 0.0f;
#pragma unroll
            for (int c = 0; c < 6; ++c) se += expf(logit[c] - mx);
            float lse = mx + logf(se);
            int yy = y[gw];
            float ly = 0.0f;
#pragma unroll
            for (int c = 0; c < 6; ++c)
                if (yy == c) ly = logit[c];
            pl[wid] = (lse - ly) * invN;
        }
    }
    __syncthreads();
    if (threadIdx.x == 0)
        partials[blockIdx.x] = pl[0] + pl[1] + pl[2] + pl[3];
}

__global__ __launch_bounds__(1024)
void loss_reduce(const float* __restrict__ partials, float* __restrict__ loss, int P)
{
    __shared__ float buf[1024];
    float s = 0.0f;
    for (int i = threadIdx.x; i < (unsigned)P; i += 1024) s += partials[i];
    buf[threadIdx.x] = s;
    __syncthreads();
    for (int o = 512; o >= 1; o >>= 1) {
        if (threadIdx.x < (unsigned)o) buf[threadIdx.x] += buf[threadIdx.x + o];
        __syncthreads();
    }
    if (threadIdx.x == 0) loss[0] = buf[0];
}

extern "C" void kernel_launch(void* const* d_in, const int* in_sizes, int n_in,
                              void* d_out, int out_size, void* d_ws, size_t ws_size,
                              hipStream_t stream)
{
    const float* x     = (const float*)d_in[0];
    const int*   eidx  = (const int*)d_in[1];
    const int*   y     = (const int*)d_in[2];
    const float* lin_w = (const float*)d_in[3];
    const float* lin_b = (const float*)d_in[4];
    const float* w1    = (const float*)d_in[5];
    const float* wih1  = (const float*)d_in[6];
    const float* whh1  = (const float*)d_in[7];
    const float* bih1  = (const float*)d_in[8];
    const float* bhh1  = (const float*)d_in[9];
    const float* w2    = (const float*)d_in[10];
    const float* wih2  = (const float*)d_in[11];
    const float* whh2  = (const float*)d_in[12];
    const float* bih2  = (const float*)d_in[13];
    const float* bhh2  = (const float*)d_in[14];
    const float* cls_w = (const float*)d_in[15];
    const float* cls_b = (const float*)d_in[16];

    const int N   = in_sizes[2];
    const int E   = in_sizes[1] / 2;
    const int DIN = in_sizes[0] / N;   // 256
    const int L   = 6;
    const size_t NH = (size_t)N * 128;
    const int P   = (N + 3) / 4;

    float* out    = (float*)d_out;
    float* logits = out;
    float* loss   = out + (size_t)N * L;
    float* feats  = out + (size_t)N * L + 1;

    float* ws   = (float*)d_ws;
    float* h    = ws;                 // NH
    float* m    = ws + NH;            // NH
    float* agg  = ws + 2 * NH;        // NH
    float* part = ws + 3 * NH;        // P

    unsigned short* linP  = (unsigned short*)(part + P);   // 256*128
    unsigned short* w1P   = linP  + 32768;                 // 128*128
    unsigned short* w2P   = w1P   + 16384;
    unsigned short* wih1P = w2P   + 16384;                 // 128*384 packed as [4][384][32]
    unsigned short* whh1P = wih1P + 49152;
    unsigned short* wih2P = whh1P + 49152;
    unsigned short* whh2P = wih2P + 49152;

    int* off    = (int*)(whh2P + 49152);   // N+1
    int* cursor = off + (N + 1);           // N
    int* ssrc   = cursor + N;              // E

    const int* src = eidx;
    const int* dst = eidx + E;

    dim3 blk(256);
    unsigned egrid  = (unsigned)((E + 255) / 256);
    unsigned ngridW = (unsigned)((N + 3) / 4);
    unsigned gemmG  = (unsigned)((N + 63) / 64);
    unsigned gruG   = (unsigned)((N + 31) / 32);

    // CSR build (once; reused by both layers)
    hipMemsetAsync(cursor, 0, (size_t)N * sizeof(int), stream);
    hist_kernel<<<dim3(egrid), blk, 0, stream>>>(dst, cursor, E);
    scan_kernel<<<dim3(1), dim3(1024), 0, stream>>>(cursor, off, N);
    hipMemcpyAsync(cursor, off, (size_t)N * sizeof(int), hipMemcpyDeviceToDevice, stream);
    sort_kernel<<<dim3(egrid), blk, 0, stream>>>(src, dst, cursor, ssrc, E);

    // weight prepack to bf16 chunks
    prepack_kernel<<<dim3(128), blk, 0, stream>>>(lin_w, linP, DIN, 128, 0);
    prepack_kernel<<<dim3(64),  blk, 0, stream>>>(w1, w1P, 128, 128, 0);
    prepack_kernel<<<dim3(64),  blk, 0, stream>>>(w2, w2P, 128, 128, 0);
    prepack_kernel<<<dim3(192), blk, 0, stream>>>(wih1, wih1P, 128, 384, 1);
    prepack_kernel<<<dim3(192), blk, 0, stream>>>(whh1, whh1P, 128, 384, 1);
    prepack_kernel<<<dim3(192), blk, 0, stream>>>(wih2, wih2P, 128, 384, 1);
    prepack_kernel<<<dim3(192), blk, 0, stream>>>(whh2, whh2P, 128, 384, 1);

    // h = x @ lin_w + lin_b
    mfma_xw<<<dim3(gemmG), blk, 0, stream>>>(x, linP, lin_b, h, N, DIN);

    // ---- layer 1 ----
    mfma_xw<<<dim3(gemmG), blk, 0, stream>>>(h, w1P, nullptr, m, N, 128);
    gather_agg<<<dim3(ngridW), blk, 0, stream>>>(m, off, ssrc, agg, N);
    mfma_gru<1><<<dim3(gruG), blk, 0, stream>>>(agg, h, wih1P, whh1P, bih1, bhh1, h, N);

    // ---- layer 2 ----
    mfma_xw<<<dim3(gemmG), blk, 0, stream>>>(h, w2P, nullptr, m, N, 128);
    gather_agg<<<dim3(ngridW), blk, 0, stream>>>(m, off, ssrc, agg, N);
    mfma_gru<0><<<dim3(gruG), blk, 0, stream>>>(agg, h, wih2P, whh2P, bih2, bhh2, feats, N);

    // ---- classifier + loss ----
    cls_kernel<<<dim3(ngridW), blk, 0, stream>>>(feats, cls_w, cls_b, y, logits, part, N, 1.0f / (float)N);
    loss_reduce<<<dim3(1), dim3(1024), 0, stream>>>(part, loss, P);
}

// Round 5
// 514.631 us; speedup vs baseline: 4.9549x; 1.0447x over previous
//
#include <hip/hip_runtime.h>
#include <cstddef>
#include <cstdint>

typedef __attribute__((ext_vector_type(8))) short bf16x8;
typedef __attribute__((ext_vector_type(4))) float f32x4;
typedef __attribute__((ext_vector_type(8))) unsigned short u16x8;

__device__ inline unsigned short f2bf(float f) {
    unsigned u = __builtin_bit_cast(unsigned, f);
    u += 0x7FFF + ((u >> 16) & 1);          // round-to-nearest-even
    return (unsigned short)(u >> 16);
}

// XOR-swizzled byte offset into a [rows][32 bf16] LDS tile (64B rows).
// Breaks the 8-way bank conflict of the 64B-stride fragment reads; bijective
// within each row (slot^((row>>1)&3)), applied at BOTH write and read.
__device__ inline int swzB(int row, int slot) {
    return row * 64 + ((slot ^ ((row >> 1) & 3)) << 4);
}
__device__ inline void stu(unsigned short* base, int u, u16x8 v) {
    *(u16x8*)((char*)base + swzB(u >> 2, u & 3)) = v;
}
__device__ inline bf16x8 ldu(const unsigned short* base, int row, int slot) {
    return *(const bf16x8*)((const char*)base + swzB(row, slot));
}

// ---------------- weight prepack: P[kc][c][kk] = Bop[k=kc*32+kk][c] ----------------
__global__ __launch_bounds__(256)
void prepack_kernel(const float* __restrict__ S, unsigned short* __restrict__ P,
                    int K, int C, int trans)
{
    int idx = blockIdx.x * 256 + threadIdx.x;
    if (idx >= K * C) return;
    int kk = idx & 31;
    int c  = (idx >> 5) % C;
    int kc = idx / (32 * C);
    int k  = kc * 32 + kk;
    float v = trans ? S[(size_t)c * K + k] : S[(size_t)k * C + c];
    P[idx] = f2bf(v);
}

// ---------------- MFMA GEMM: C[M,128] = A[M,K] @ W (+bias), W pre-packed bf16 ----------------
__global__ __launch_bounds__(256)
void mfma_xw(const float* __restrict__ A, const unsigned short* __restrict__ P,
             const float* __restrict__ bias, float* __restrict__ C, int M, int K)
{
    __shared__ unsigned short Ab[64 * 32];
    __shared__ unsigned short Bb[128 * 32];
    const int tid  = threadIdx.x;
    const int l    = tid & 63;
    const int w    = tid >> 6;
    const int wr   = w >> 1, wc = w & 1;
    const int row0 = blockIdx.x * 64;

    f32x4 acc[2][4];
#pragma unroll
    for (int i = 0; i < 2; ++i)
#pragma unroll
        for (int j = 0; j < 4; ++j) acc[i][j] = (f32x4){0.f, 0.f, 0.f, 0.f};

    const int KC = K >> 5;
    for (int kc = 0; kc < KC; ++kc) {
        {   // stage A: 64 rows x 32 k, f32 -> bf16, swizzled
            int row = tid >> 2, slot = tid & 3, kpos = slot * 8;
            unsigned short u[8];
            if (row0 + row < M) {
                const float* src = &A[(size_t)(row0 + row) * K + kc * 32 + kpos];
                float4 v0 = *(const float4*)src;
                float4 v1 = *(const float4*)(src + 4);
                u[0]=f2bf(v0.x); u[1]=f2bf(v0.y); u[2]=f2bf(v0.z); u[3]=f2bf(v0.w);
                u[4]=f2bf(v1.x); u[5]=f2bf(v1.y); u[6]=f2bf(v1.z); u[7]=f2bf(v1.w);
            } else {
#pragma unroll
                for (int q = 0; q < 8; ++q) u[q] = 0;
            }
            stu(Ab, tid, *(u16x8*)u);
        }
        {   // stage B: copy packed chunk (128x32 bf16 = 512 units), swizzled
            const u16x8* src = (const u16x8*)(P + (size_t)kc * 4096);
            stu(Bb, tid * 2,     src[tid * 2]);
            stu(Bb, tid * 2 + 1, src[tid * 2 + 1]);
        }
        __syncthreads();
        bf16x8 af[2], bf[4];
#pragma unroll
        for (int rt = 0; rt < 2; ++rt)
            af[rt] = ldu(Ab, wr * 32 + rt * 16 + (l & 15), l >> 4);
#pragma unroll
        for (int ct = 0; ct < 4; ++ct)
            bf[ct] = ldu(Bb, wc * 64 + ct * 16 + (l & 15), l >> 4);
#pragma unroll
        for (int rt = 0; rt < 2; ++rt)
#pragma unroll
            for (int ct = 0; ct < 4; ++ct)
                acc[rt][ct] = __builtin_amdgcn_mfma_f32_16x16x32_bf16(af[rt], bf[ct], acc[rt][ct], 0, 0, 0);
        __syncthreads();
    }

#pragma unroll
    for (int rt = 0; rt < 2; ++rt)
#pragma unroll
        for (int ct = 0; ct < 4; ++ct) {
            int col = wc * 64 + ct * 16 + (l & 15);
            float bv = bias ? bias[col] : 0.0f;
#pragma unroll
            for (int j = 0; j < 4; ++j) {
                int row = row0 + wr * 32 + rt * 16 + (l >> 4) * 4 + j;
                if (row < M) C[(size_t)row * 128 + col] = acc[rt][ct][j] + bv;
            }
        }
}

// ---------------- fused gi/gh GEMMs + GRU ----------------
// 1024 threads = 16 waves; BM=64 rows. Wave w: r=w>>3 (rows r*32..+31),
// g=w&7 (GRU units g*16..+15 -> complete (r,z,n) col triples, no exchange).
template<int ELU>
__global__ __launch_bounds__(1024)
void mfma_gru(const float* __restrict__ agg, const float* __restrict__ hin,
              const unsigned short* __restrict__ wihP, const unsigned short* __restrict__ whhP,
              const float* __restrict__ bih, const float* __restrict__ bhh,
              float* __restrict__ hout, int M)
{
    __shared__ unsigned short Aa[64 * 32];
    __shared__ unsigned short Ah[64 * 32];
    __shared__ unsigned short Bw[384 * 32];
    __shared__ unsigned short Bu[384 * 32];
    const int tid = threadIdx.x;
    const int l   = tid & 63;
    const int w   = tid >> 6;
    const int r   = w >> 3, g = w & 7;
    const int row0 = blockIdx.x * 64;

    f32x4 gi[3][2], gh[3][2];   // [group r/z/n][rowtile]
#pragma unroll
    for (int gr = 0; gr < 3; ++gr)
#pragma unroll
        for (int rt = 0; rt < 2; ++rt) {
            gi[gr][rt] = (f32x4){0.f, 0.f, 0.f, 0.f};
            gh[gr][rt] = (f32x4){0.f, 0.f, 0.f, 0.f};
        }

    for (int kc = 0; kc < 4; ++kc) {
        // stage B: 2 chunks of 384x32 bf16 = 1536 units each.
        const u16x8* sw = (const u16x8*)(wihP + (size_t)kc * 12288);
        const u16x8* su = (const u16x8*)(whhP + (size_t)kc * 12288);
        stu(Bw, tid, sw[tid]);
        stu(Bu, tid, su[tid]);
        if (tid < 512) {
            int u1 = 1024 + tid;
            stu(Bw, u1, sw[u1]);
            stu(Bu, u1, su[u1]);
        } else {
            // stage A (agg + h): 64 rows x 32 k each, f32 -> bf16
            int t2 = tid - 512;
            int mat = t2 >> 8;                 // 0: agg, 1: h
            int t3 = t2 & 255;
            int row = t3 >> 2, slot = t3 & 3, kpos = slot * 8;
            const float* srcM = mat ? hin : agg;
            unsigned short* dstL = mat ? Ah : Aa;
            unsigned short u[8];
            if (row0 + row < M) {
                const float* src = &srcM[(size_t)(row0 + row) * 128 + kc * 32 + kpos];
                float4 v0 = *(const float4*)src;
                float4 v1 = *(const float4*)(src + 4);
                u[0]=f2bf(v0.x); u[1]=f2bf(v0.y); u[2]=f2bf(v0.z); u[3]=f2bf(v0.w);
                u[4]=f2bf(v1.x); u[5]=f2bf(v1.y); u[6]=f2bf(v1.z); u[7]=f2bf(v1.w);
            } else {
#pragma unroll
                for (int q = 0; q < 8; ++q) u[q] = 0;
            }
            *(u16x8*)((char*)dstL + swzB(row, slot)) = *(u16x8*)u;
        }
        __syncthreads();

        bf16x8 aa[2], ah[2];
#pragma unroll
        for (int rt = 0; rt < 2; ++rt) {
            aa[rt] = ldu(Aa, r * 32 + rt * 16 + (l & 15), l >> 4);
            ah[rt] = ldu(Ah, r * 32 + rt * 16 + (l & 15), l >> 4);
        }
#pragma unroll
        for (int gr = 0; gr < 3; ++gr) {
            int c = gr * 128 + g * 16 + (l & 15);
            bf16x8 bw = ldu(Bw, c, l >> 4);
            bf16x8 bu = ldu(Bu, c, l >> 4);
#pragma unroll
            for (int rt = 0; rt < 2; ++rt) {
                gi[gr][rt] = __builtin_amdgcn_mfma_f32_16x16x32_bf16(aa[rt], bw, gi[gr][rt], 0, 0, 0);
                gh[gr][rt] = __builtin_amdgcn_mfma_f32_16x16x32_bf16(ah[rt], bu, gh[gr][rt], 0, 0, 0);
            }
        }
        __syncthreads();
    }

    // GRU epilogue (each wave owns complete triples for units g*16..+15)
    {
        int unit = g * 16 + (l & 15);
        float bir = bih[unit], biz = bih[128 + unit], bin = bih[256 + unit];
        float bhr = bhh[unit], bhz = bhh[128 + unit], bhn = bhh[256 + unit];
#pragma unroll
        for (int rt = 0; rt < 2; ++rt)
#pragma unroll
            for (int j = 0; j < 4; ++j) {
                int row = row0 + r * 32 + rt * 16 + (l >> 4) * 4 + j;
                if (row >= M) continue;
                float ir  = gi[0][rt][j] + bir;
                float iz  = gi[1][rt][j] + biz;
                float in_ = gi[2][rt][j] + bin;
                float hr  = gh[0][rt][j] + bhr;
                float hz  = gh[1][rt][j] + bhz;
                float hn  = gh[2][rt][j] + bhn;
                float hv  = hin[(size_t)row * 128 + unit];
                float rr = 1.0f / (1.0f + expf(-(ir + hr)));
                float z  = 1.0f / (1.0f + expf(-(iz + hz)));
                float nn = tanhf(in_ + rr * hn);
                float o  = (1.0f - z) * nn + z * hv;
                if (ELU) o = (o > 0.0f) ? o : expm1f(o);
                hout[(size_t)row * 128 + unit] = o;
            }
    }
}

// ---------------- CSR build (counting sort of edges by dst) ----------------

__global__ __launch_bounds__(256)
void hist_kernel(const int* __restrict__ dst, int* __restrict__ deg, int E)
{
    int e = blockIdx.x * 256 + threadIdx.x;
    if (e < E) atomicAdd(&deg[dst[e]], 1);
}

__global__ __launch_bounds__(1024)
void scan_kernel(const int* __restrict__ deg, int* __restrict__ off, int N)
{
    __shared__ int buf[1024];
    __shared__ int carry;
    if (threadIdx.x == 0) carry = 0;
    __syncthreads();
    for (int base = 0; base < N; base += 1024) {
        int i = base + (int)threadIdx.x;
        int v = (i < N) ? deg[i] : 0;
        buf[threadIdx.x] = v;
        __syncthreads();
        for (int o = 1; o < 1024; o <<= 1) {
            int t = (threadIdx.x >= (unsigned)o) ? buf[threadIdx.x - o] : 0;
            __syncthreads();
            buf[threadIdx.x] += t;
            __syncthreads();
        }
        if (i < N) off[i] = carry + buf[threadIdx.x] - v;
        __syncthreads();
        if (threadIdx.x == 1023) carry += buf[1023];
        __syncthreads();
    }
    if (threadIdx.x == 0) off[N] = carry;
}

__global__ __launch_bounds__(256)
void sort_kernel(const int* __restrict__ src, const int* __restrict__ dst,
                 int* __restrict__ cursor, int* __restrict__ ssrc, int E)
{
    int e = blockIdx.x * 256 + threadIdx.x;
    if (e >= E) return;
    int pos = atomicAdd(&cursor[dst[e]], 1);
    ssrc[pos] = src[e];
}

// one wave per dst node: agg[n] = sum over incoming edges of m[ssrc[e]]
__global__ __launch_bounds__(256)
void gather_agg(const float* __restrict__ m, const int* __restrict__ off,
                const int* __restrict__ ssrc, float* __restrict__ agg, int N)
{
    int w = (blockIdx.x * 256 + threadIdx.x) >> 6;
    int lane = threadIdx.x & 63;
    if (w >= N) return;
    int e0 = off[w], e1 = off[w + 1];
    float2 a0 = make_float2(0.f, 0.f), a1 = make_float2(0.f, 0.f);
    int e = e0;
    for (; e + 1 < e1; e += 2) {
        int s0 = ssrc[e], s1 = ssrc[e + 1];
        float2 v0 = *(const float2*)&m[(size_t)s0 * 128 + lane * 2];
        float2 v1 = *(const float2*)&m[(size_t)s1 * 128 + lane * 2];
        a0.x += v0.x; a0.y += v0.y;
        a1.x += v1.x; a1.y += v1.y;
    }
    if (e < e1) {
        int s0 = ssrc[e];
        float2 v0 = *(const float2*)&m[(size_t)s0 * 128 + lane * 2];
        a0.x += v0.x; a0.y += v0.y;
    }
    a0.x += a1.x; a0.y += a1.y;
    *(float2*)&agg[(size_t)w * 128 + lane * 2] = a0;
}

// one wave per node: logits = h@W + b ; log_softmax ; per-block partial loss
__global__ __launch_bounds__(256)
void cls_kernel(const float* __restrict__ h, const float* __restrict__ W,
                const float* __restrict__ b, const int* __restrict__ y,
                float* __restrict__ logitsOut, float* __restrict__ partials,
                int N, float invN)
{
    __shared__ float pl[4];
    const int wid  = threadIdx.x >> 6;
    const int lane = threadIdx.x & 63;
    const int gw   = blockIdx.x * 4 + wid;
    if (threadIdx.x < 4) pl[threadIdx.x] = 0.0f;
    __syncthreads();
    if (gw < N) {
        float h0 = h[(size_t)gw * 128 + lane * 2];
        float h1 = h[(size_t)gw * 128 + lane * 2 + 1];
        float acc[6];
#pragma unroll
        for (int c = 0; c < 6; ++c)
            acc[c] = h0 * W[(lane * 2) * 6 + c] + h1 * W[(lane * 2 + 1) * 6 + c];
#pragma unroll
        for (int off = 32; off >= 1; off >>= 1)
#pragma unroll
            for (int c = 0; c < 6; ++c)
                acc[c] += __shfl_xor(acc[c], off, 64);
        float logit[6];
#pragma unroll
        for (int c = 0; c < 6; ++c) logit[c] = acc[c] + b[c];
#pragma unroll
        for (int c = 0; c < 6; ++c)
            if (lane == c) logitsOut[(size_t)gw * 6 + c] = logit[c];
        if (lane == 0) {
            float mx = logit[0];
#pragma unroll
            for (int c = 1; c < 6; ++c) mx = fmaxf(mx, logit[c]);
            float se = 0.0f;
#pragma unroll
            for (int c = 0; c < 6; ++c) se += expf(logit[c] - mx);
            float lse = mx + logf(se);
            int yy = y[gw];
            float ly = 0.0f;
#pragma unroll
            for (int c = 0; c < 6; ++c)
                if (yy == c) ly = logit[c];
            pl[wid] = (lse - ly) * invN;
        }
    }
    __syncthreads();
    if (threadIdx.x == 0)
        partials[blockIdx.x] = pl[0] + pl[1] + pl[2] + pl[3];
}

__global__ __launch_bounds__(1024)
void loss_reduce(const float* __restrict__ partials, float* __restrict__ loss, int P)
{
    __shared__ float buf[1024];
    float s = 0.0f;
    for (int i = threadIdx.x; i < (unsigned)P; i += 1024) s += partials[i];
    buf[threadIdx.x] = s;
    __syncthreads();
    for (int o = 512; o >= 1; o >>= 1) {
        if (threadIdx.x < (unsigned)o) buf[threadIdx.x] += buf[threadIdx.x + o];
        __syncthreads();
    }
    if (threadIdx.x == 0) loss[0] = buf[0];
}

extern "C" void kernel_launch(void* const* d_in, const int* in_sizes, int n_in,
                              void* d_out, int out_size, void* d_ws, size_t ws_size,
                              hipStream_t stream)
{
    const float* x     = (const float*)d_in[0];
    const int*   eidx  = (const int*)d_in[1];
    const int*   y     = (const int*)d_in[2];
    const float* lin_w = (const float*)d_in[3];
    const float* lin_b = (const float*)d_in[4];
    const float* w1    = (const float*)d_in[5];
    const float* wih1  = (const float*)d_in[6];
    const float* whh1  = (const float*)d_in[7];
    const float* bih1  = (const float*)d_in[8];
    const float* bhh1  = (const float*)d_in[9];
    const float* w2    = (const float*)d_in[10];
    const float* wih2  = (const float*)d_in[11];
    const float* whh2  = (const float*)d_in[12];
    const float* bih2  = (const float*)d_in[13];
    const float* bhh2  = (const float*)d_in[14];
    const float* cls_w = (const float*)d_in[15];
    const float* cls_b = (const float*)d_in[16];

    const int N   = in_sizes[2];
    const int E   = in_sizes[1] / 2;
    const int DIN = in_sizes[0] / N;   // 256
    const int L   = 6;
    const size_t NH = (size_t)N * 128;
    const int P   = (N + 3) / 4;

    float* out    = (float*)d_out;
    float* logits = out;
    float* loss   = out + (size_t)N * L;
    float* feats  = out + (size_t)N * L + 1;

    float* ws   = (float*)d_ws;
    float* h    = ws;                 // NH
    float* m    = ws + NH;            // NH
    float* agg  = ws + 2 * NH;        // NH
    float* part = ws + 3 * NH;        // P

    unsigned short* linP  = (unsigned short*)(part + P);   // 256*128
    unsigned short* w1P   = linP  + 32768;                 // 128*128
    unsigned short* w2P   = w1P   + 16384;
    unsigned short* wih1P = w2P   + 16384;                 // 128*384 packed as [4][384][32]
    unsigned short* whh1P = wih1P + 49152;
    unsigned short* wih2P = whh1P + 49152;
    unsigned short* whh2P = wih2P + 49152;

    int* off    = (int*)(whh2P + 49152);   // N+1
    int* cursor = off + (N + 1);           // N
    int* ssrc   = cursor + N;              // E

    const int* src = eidx;
    const int* dst = eidx + E;

    dim3 blk(256);
    unsigned egrid  = (unsigned)((E + 255) / 256);
    unsigned ngridW = (unsigned)((N + 3) / 4);
    unsigned gemmG  = (unsigned)((N + 63) / 64);
    unsigned gruG   = (unsigned)((N + 63) / 64);

    // CSR build (once; reused by both layers)
    hipMemsetAsync(cursor, 0, (size_t)N * sizeof(int), stream);
    hist_kernel<<<dim3(egrid), blk, 0, stream>>>(dst, cursor, E);
    scan_kernel<<<dim3(1), dim3(1024), 0, stream>>>(cursor, off, N);
    hipMemcpyAsync(cursor, off, (size_t)N * sizeof(int), hipMemcpyDeviceToDevice, stream);
    sort_kernel<<<dim3(egrid), blk, 0, stream>>>(src, dst, cursor, ssrc, E);

    // weight prepack to bf16 chunks
    prepack_kernel<<<dim3(128), blk, 0, stream>>>(lin_w, linP, DIN, 128, 0);
    prepack_kernel<<<dim3(64),  blk, 0, stream>>>(w1, w1P, 128, 128, 0);
    prepack_kernel<<<dim3(64),  blk, 0, stream>>>(w2, w2P, 128, 128, 0);
    prepack_kernel<<<dim3(192), blk, 0, stream>>>(wih1, wih1P, 128, 384, 1);
    prepack_kernel<<<dim3(192), blk, 0, stream>>>(whh1, whh1P, 128, 384, 1);
    prepack_kernel<<<dim3(192), blk, 0, stream>>>(wih2, wih2P, 128, 384, 1);
    prepack_kernel<<<dim3(192), blk, 0, stream>>>(whh2, whh2P, 128, 384, 1);

    // h = x @ lin_w + lin_b
    mfma_xw<<<dim3(gemmG), blk, 0, stream>>>(x, linP, lin_b, h, N, DIN);

    // ---- layer 1 ----
    mfma_xw<<<dim3(gemmG), blk, 0, stream>>>(h, w1P, nullptr, m, N, 128);
    gather_agg<<<dim3(ngridW), blk, 0, stream>>>(m, off, ssrc, agg, N);
    mfma_gru<1><<<dim3(gruG), dim3(1024), 0, stream>>>(agg, h, wih1P, whh1P, bih1, bhh1, h, N);

    // ---- layer 2 ----
    mfma_xw<<<dim3(gemmG), blk, 0, stream>>>(h, w2P, nullptr, m, N, 128);
    gather_agg<<<dim3(ngridW), blk, 0, stream>>>(m, off, ssrc, agg, N);
    mfma_gru<0><<<dim3(gruG), dim3(1024), 0, stream>>>(agg, h, wih2P, whh2P, bih2, bhh2, feats, N);

    // ---- classifier + loss ----
    cls_kernel<<<dim3(ngridW), blk, 0, stream>>>(feats, cls_w, cls_b, y, logits, part, N, 1.0f / (float)N);
    loss_reduce<<<dim3(1), dim3(1024), 0, stream>>>(part, loss, P);
}

// Round 6
// 431.461 us; speedup vs baseline: 5.9100x; 1.1928x over previous
//
#include <hip/hip_runtime.h>
#include <cstddef>
#include <cstdint>

typedef __attribute__((ext_vector_type(8))) short bf16x8;
typedef __attribute__((ext_vector_type(4))) float f32x4;
typedef __attribute__((ext_vector_type(8))) unsigned short u16x8;

__device__ inline unsigned short f2bf(float f) {
    unsigned u = __builtin_bit_cast(unsigned, f);
    u += 0x7FFF + ((u >> 16) & 1);          // round-to-nearest-even
    return (unsigned short)(u >> 16);
}

// XOR-swizzled byte offset into a [rows][32 bf16] LDS tile (64B rows).
__device__ inline int swzB(int row, int slot) {
    return row * 64 + ((slot ^ ((row >> 1) & 3)) << 4);
}
__device__ inline void stu(unsigned short* base, int u, u16x8 v) {
    *(u16x8*)((char*)base + swzB(u >> 2, u & 3)) = v;
}
__device__ inline bf16x8 ldu(const unsigned short* base, int row, int slot) {
    return *(const bf16x8*)((const char*)base + swzB(row, slot));
}

// ---------------- weight prepack: P[kc][c][kk] = Bop[k=kc*32+kk][c] ----------------
__global__ __launch_bounds__(256)
void prepack_kernel(const float* __restrict__ S, unsigned short* __restrict__ P,
                    int K, int C, int trans)
{
    int idx = blockIdx.x * 256 + threadIdx.x;
    if (idx >= K * C) return;
    int kk = idx & 31;
    int c  = (idx >> 5) % C;
    int kc = idx / (32 * C);
    int k  = kc * 32 + kk;
    float v = trans ? S[(size_t)c * K + k] : S[(size_t)k * C + c];
    P[idx] = f2bf(v);
}

// ---------------- MFMA GEMM: C[M,128] = A[M,K] @ W (+bias), W pre-packed bf16 ----------------
__global__ __launch_bounds__(256)
void mfma_xw(const float* __restrict__ A, const unsigned short* __restrict__ P,
             const float* __restrict__ bias, float* __restrict__ C, int M, int K)
{
    __shared__ unsigned short Ab[64 * 32];
    __shared__ unsigned short Bb[128 * 32];
    const int tid  = threadIdx.x;
    const int l    = tid & 63;
    const int w    = tid >> 6;
    const int wr   = w >> 1, wc = w & 1;
    const int row0 = blockIdx.x * 64;

    f32x4 acc[2][4];
#pragma unroll
    for (int i = 0; i < 2; ++i)
#pragma unroll
        for (int j = 0; j < 4; ++j) acc[i][j] = (f32x4){0.f, 0.f, 0.f, 0.f};

    const int KC = K >> 5;
    for (int kc = 0; kc < KC; ++kc) {
        {   // stage A: 64 rows x 32 k, f32 -> bf16, swizzled
            int row = tid >> 2, slot = tid & 3, kpos = slot * 8;
            unsigned short u[8];
            if (row0 + row < M) {
                const float* src = &A[(size_t)(row0 + row) * K + kc * 32 + kpos];
                float4 v0 = *(const float4*)src;
                float4 v1 = *(const float4*)(src + 4);
                u[0]=f2bf(v0.x); u[1]=f2bf(v0.y); u[2]=f2bf(v0.z); u[3]=f2bf(v0.w);
                u[4]=f2bf(v1.x); u[5]=f2bf(v1.y); u[6]=f2bf(v1.z); u[7]=f2bf(v1.w);
            } else {
#pragma unroll
                for (int q = 0; q < 8; ++q) u[q] = 0;
            }
            stu(Ab, tid, *(u16x8*)u);
        }
        {   // stage B: copy packed chunk (128x32 bf16 = 512 units), swizzled
            const u16x8* src = (const u16x8*)(P + (size_t)kc * 4096);
            stu(Bb, tid * 2,     src[tid * 2]);
            stu(Bb, tid * 2 + 1, src[tid * 2 + 1]);
        }
        __syncthreads();
        bf16x8 af[2], bf[4];
#pragma unroll
        for (int rt = 0; rt < 2; ++rt)
            af[rt] = ldu(Ab, wr * 32 + rt * 16 + (l & 15), l >> 4);
#pragma unroll
        for (int ct = 0; ct < 4; ++ct)
            bf[ct] = ldu(Bb, wc * 64 + ct * 16 + (l & 15), l >> 4);
#pragma unroll
        for (int rt = 0; rt < 2; ++rt)
#pragma unroll
            for (int ct = 0; ct < 4; ++ct)
                acc[rt][ct] = __builtin_amdgcn_mfma_f32_16x16x32_bf16(af[rt], bf[ct], acc[rt][ct], 0, 0, 0);
        __syncthreads();
    }

#pragma unroll
    for (int rt = 0; rt < 2; ++rt)
#pragma unroll
        for (int ct = 0; ct < 4; ++ct) {
            int col = wc * 64 + ct * 16 + (l & 15);
            float bv = bias ? bias[col] : 0.0f;
#pragma unroll
            for (int j = 0; j < 4; ++j) {
                int row = row0 + wr * 32 + rt * 16 + (l >> 4) * 4 + j;
                if (row < M) C[(size_t)row * 128 + col] = acc[rt][ct][j] + bv;
            }
        }
}

// ---------------- fused gi/gh GEMMs + GRU ----------------
template<int ELU>
__global__ __launch_bounds__(1024)
void mfma_gru(const float* __restrict__ agg, const float* __restrict__ hin,
              const unsigned short* __restrict__ wihP, const unsigned short* __restrict__ whhP,
              const float* __restrict__ bih, const float* __restrict__ bhh,
              float* __restrict__ hout, int M)
{
    __shared__ unsigned short Aa[64 * 32];
    __shared__ unsigned short Ah[64 * 32];
    __shared__ unsigned short Bw[384 * 32];
    __shared__ unsigned short Bu[384 * 32];
    const int tid = threadIdx.x;
    const int l   = tid & 63;
    const int w   = tid >> 6;
    const int r   = w >> 3, g = w & 7;
    const int row0 = blockIdx.x * 64;

    f32x4 gi[3][2], gh[3][2];
#pragma unroll
    for (int gr = 0; gr < 3; ++gr)
#pragma unroll
        for (int rt = 0; rt < 2; ++rt) {
            gi[gr][rt] = (f32x4){0.f, 0.f, 0.f, 0.f};
            gh[gr][rt] = (f32x4){0.f, 0.f, 0.f, 0.f};
        }

    for (int kc = 0; kc < 4; ++kc) {
        const u16x8* sw = (const u16x8*)(wihP + (size_t)kc * 12288);
        const u16x8* su = (const u16x8*)(whhP + (size_t)kc * 12288);
        stu(Bw, tid, sw[tid]);
        stu(Bu, tid, su[tid]);
        if (tid < 512) {
            int u1 = 1024 + tid;
            stu(Bw, u1, sw[u1]);
            stu(Bu, u1, su[u1]);
        } else {
            int t2 = tid - 512;
            int mat = t2 >> 8;
            int t3 = t2 & 255;
            int row = t3 >> 2, slot = t3 & 3, kpos = slot * 8;
            const float* srcM = mat ? hin : agg;
            unsigned short* dstL = mat ? Ah : Aa;
            unsigned short u[8];
            if (row0 + row < M) {
                const float* src = &srcM[(size_t)(row0 + row) * 128 + kc * 32 + kpos];
                float4 v0 = *(const float4*)src;
                float4 v1 = *(const float4*)(src + 4);
                u[0]=f2bf(v0.x); u[1]=f2bf(v0.y); u[2]=f2bf(v0.z); u[3]=f2bf(v0.w);
                u[4]=f2bf(v1.x); u[5]=f2bf(v1.y); u[6]=f2bf(v1.z); u[7]=f2bf(v1.w);
            } else {
#pragma unroll
                for (int q = 0; q < 8; ++q) u[q] = 0;
            }
            *(u16x8*)((char*)dstL + swzB(row, slot)) = *(u16x8*)u;
        }
        __syncthreads();

        bf16x8 aa[2], ah[2];
#pragma unroll
        for (int rt = 0; rt < 2; ++rt) {
            aa[rt] = ldu(Aa, r * 32 + rt * 16 + (l & 15), l >> 4);
            ah[rt] = ldu(Ah, r * 32 + rt * 16 + (l & 15), l >> 4);
        }
#pragma unroll
        for (int gr = 0; gr < 3; ++gr) {
            int c = gr * 128 + g * 16 + (l & 15);
            bf16x8 bw = ldu(Bw, c, l >> 4);
            bf16x8 bu = ldu(Bu, c, l >> 4);
#pragma unroll
            for (int rt = 0; rt < 2; ++rt) {
                gi[gr][rt] = __builtin_amdgcn_mfma_f32_16x16x32_bf16(aa[rt], bw, gi[gr][rt], 0, 0, 0);
                gh[gr][rt] = __builtin_amdgcn_mfma_f32_16x16x32_bf16(ah[rt], bu, gh[gr][rt], 0, 0, 0);
            }
        }
        __syncthreads();
    }

    {
        int unit = g * 16 + (l & 15);
        float bir = bih[unit], biz = bih[128 + unit], bin = bih[256 + unit];
        float bhr = bhh[unit], bhz = bhh[128 + unit], bhn = bhh[256 + unit];
#pragma unroll
        for (int rt = 0; rt < 2; ++rt)
#pragma unroll
            for (int j = 0; j < 4; ++j) {
                int row = row0 + r * 32 + rt * 16 + (l >> 4) * 4 + j;
                if (row >= M) continue;
                float ir  = gi[0][rt][j] + bir;
                float iz  = gi[1][rt][j] + biz;
                float in_ = gi[2][rt][j] + bin;
                float hr  = gh[0][rt][j] + bhr;
                float hz  = gh[1][rt][j] + bhz;
                float hn  = gh[2][rt][j] + bhn;
                float hv  = hin[(size_t)row * 128 + unit];
                float rr = 1.0f / (1.0f + expf(-(ir + hr)));
                float z  = 1.0f / (1.0f + expf(-(iz + hz)));
                float nn = tanhf(in_ + rr * hn);
                float o  = (1.0f - z) * nn + z * hv;
                if (ELU) o = (o > 0.0f) ? o : expm1f(o);
                hout[(size_t)row * 128 + unit] = o;
            }
    }
}

// ---------------- CSR build (counting sort of edges by dst) ----------------

__global__ __launch_bounds__(256)
void hist_kernel(const int* __restrict__ dst, int* __restrict__ deg, int E)
{
    int e = blockIdx.x * 256 + threadIdx.x;
    if (e < E) atomicAdd(&deg[dst[e]], 1);
}

// multi-block scan, stage 1: block-local exclusive scan + block totals
__global__ __launch_bounds__(1024)
void scan1_kernel(const int* __restrict__ deg, int* __restrict__ off,
                  int* __restrict__ bsum, int N)
{
    __shared__ int wsum[16];
    const int t = threadIdx.x, lane = t & 63, w = t >> 6;
    const int i = blockIdx.x * 1024 + t;
    int v = (i < N) ? deg[i] : 0;
    int s = v;
#pragma unroll
    for (int o = 1; o < 64; o <<= 1) {
        int n = __shfl_up(s, o, 64);
        if (lane >= o) s += n;
    }
    if (lane == 63) wsum[w] = s;
    __syncthreads();
    if (w == 0) {
        int x = (lane < 16) ? wsum[lane] : 0;
#pragma unroll
        for (int o = 1; o < 16; o <<= 1) {
            int n = __shfl_up(x, o, 64);
            if (lane >= o) x += n;
        }
        if (lane < 16) wsum[lane] = x;   // inclusive wave totals
    }
    __syncthreads();
    int woff = (w == 0) ? 0 : wsum[w - 1];
    if (i < N) off[i] = woff + s - v;    // block-local exclusive
    if (t == 0) bsum[blockIdx.x] = wsum[15];
}

// stage 2: single block scans block totals (NB <= 1024) -> exclusive prefixes
__global__ __launch_bounds__(1024)
void scan2_kernel(const int* __restrict__ bsum, int* __restrict__ bpre, int NB)
{
    __shared__ int buf[1024];
    int t = threadIdx.x;
    int v = (t < NB) ? bsum[t] : 0;
    buf[t] = v;
    __syncthreads();
    for (int o = 1; o < 1024; o <<= 1) {
        int n = (t >= o) ? buf[t - o] : 0;
        __syncthreads();
        buf[t] += n;
        __syncthreads();
    }
    if (t < NB) bpre[t] = buf[t] - v;
}

// stage 3: add block prefixes; write off and cursor (fused copy)
__global__ __launch_bounds__(1024)
void scan3_kernel(int* __restrict__ off, int* __restrict__ cursor,
                  const int* __restrict__ bpre, int N, int E)
{
    int i = blockIdx.x * 1024 + threadIdx.x;
    if (i < N) {
        int v = off[i] + bpre[blockIdx.x];
        off[i] = v;
        cursor[i] = v;
    }
    if (i == 0) off[N] = E;
}

__global__ __launch_bounds__(256)
void sort_kernel(const int* __restrict__ src, const int* __restrict__ dst,
                 int* __restrict__ cursor, int* __restrict__ ssrc, int E)
{
    int e = blockIdx.x * 256 + threadIdx.x;
    if (e >= E) return;
    int pos = atomicAdd(&cursor[dst[e]], 1);
    ssrc[pos] = src[e];
}

// one wave per dst node: agg[n] = sum over incoming edges of m[ssrc[e]]
__global__ __launch_bounds__(256)
void gather_agg(const float* __restrict__ m, const int* __restrict__ off,
                const int* __restrict__ ssrc, float* __restrict__ agg, int N)
{
    int w = (blockIdx.x * 256 + threadIdx.x) >> 6;
    int lane = threadIdx.x & 63;
    if (w >= N) return;
    int e0 = off[w], e1 = off[w + 1];
    float2 a0 = make_float2(0.f, 0.f), a1 = make_float2(0.f, 0.f);
    int e = e0;
    for (; e + 1 < e1; e += 2) {
        int s0 = ssrc[e], s1 = ssrc[e + 1];
        float2 v0 = *(const float2*)&m[(size_t)s0 * 128 + lane * 2];
        float2 v1 = *(const float2*)&m[(size_t)s1 * 128 + lane * 2];
        a0.x += v0.x; a0.y += v0.y;
        a1.x += v1.x; a1.y += v1.y;
    }
    if (e < e1) {
        int s0 = ssrc[e];
        float2 v0 = *(const float2*)&m[(size_t)s0 * 128 + lane * 2];
        a0.x += v0.x; a0.y += v0.y;
    }
    a0.x += a1.x; a0.y += a1.y;
    *(float2*)&agg[(size_t)w * 128 + lane * 2] = a0;
}

// one wave per node: logits = h@W + b ; log_softmax ; per-block partial loss
__global__ __launch_bounds__(256)
void cls_kernel(const float* __restrict__ h, const float* __restrict__ W,
                const float* __restrict__ b, const int* __restrict__ y,
                float* __restrict__ logitsOut, float* __restrict__ partials,
                int N, float invN)
{
    __shared__ float pl[4];
    const int wid  = threadIdx.x >> 6;
    const int lane = threadIdx.x & 63;
    const int gw   = blockIdx.x * 4 + wid;
    if (threadIdx.x < 4) pl[threadIdx.x] = 0.0f;
    __syncthreads();
    if (gw < N) {
        float h0 = h[(size_t)gw * 128 + lane * 2];
        float h1 = h[(size_t)gw * 128 + lane * 2 + 1];
        float acc[6];
#pragma unroll
        for (int c = 0; c < 6; ++c)
            acc[c] = h0 * W[(lane * 2) * 6 + c] + h1 * W[(lane * 2 + 1) * 6 + c];
#pragma unroll
        for (int off = 32; off >= 1; off >>= 1)
#pragma unroll
            for (int c = 0; c < 6; ++c)
                acc[c] += __shfl_xor(acc[c], off, 64);
        float logit[6];
#pragma unroll
        for (int c = 0; c < 6; ++c) logit[c] = acc[c] + b[c];
#pragma unroll
        for (int c = 0; c < 6; ++c)
            if (lane == c) logitsOut[(size_t)gw * 6 + c] = logit[c];
        if (lane == 0) {
            float mx = logit[0];
#pragma unroll
            for (int c = 1; c < 6; ++c) mx = fmaxf(mx, logit[c]);
            float se = 0.0f;
#pragma unroll
            for (int c = 0; c < 6; ++c) se += expf(logit[c] - mx);
            float lse = mx + logf(se);
            int yy = y[gw];
            float ly = 0.0f;
#pragma unroll
            for (int c = 0; c < 6; ++c)
                if (yy == c) ly = logit[c];
            pl[wid] = (lse - ly) * invN;
        }
    }
    __syncthreads();
    if (threadIdx.x == 0)
        partials[blockIdx.x] = pl[0] + pl[1] + pl[2] + pl[3];
}

__global__ __launch_bounds__(1024)
void loss_reduce(const float* __restrict__ partials, float* __restrict__ loss, int P)
{
    __shared__ float buf[1024];
    float s = 0.0f;
    for (int i = threadIdx.x; i < (unsigned)P; i += 1024) s += partials[i];
    buf[threadIdx.x] = s;
    __syncthreads();
    for (int o = 512; o >= 1; o >>= 1) {
        if (threadIdx.x < (unsigned)o) buf[threadIdx.x] += buf[threadIdx.x + o];
        __syncthreads();
    }
    if (threadIdx.x == 0) loss[0] = buf[0];
}

extern "C" void kernel_launch(void* const* d_in, const int* in_sizes, int n_in,
                              void* d_out, int out_size, void* d_ws, size_t ws_size,
                              hipStream_t stream)
{
    const float* x     = (const float*)d_in[0];
    const int*   eidx  = (const int*)d_in[1];
    const int*   y     = (const int*)d_in[2];
    const float* lin_w = (const float*)d_in[3];
    const float* lin_b = (const float*)d_in[4];
    const float* w1    = (const float*)d_in[5];
    const float* wih1  = (const float*)d_in[6];
    const float* whh1  = (const float*)d_in[7];
    const float* bih1  = (const float*)d_in[8];
    const float* bhh1  = (const float*)d_in[9];
    const float* w2    = (const float*)d_in[10];
    const float* wih2  = (const float*)d_in[11];
    const float* whh2  = (const float*)d_in[12];
    const float* bih2  = (const float*)d_in[13];
    const float* bhh2  = (const float*)d_in[14];
    const float* cls_w = (const float*)d_in[15];
    const float* cls_b = (const float*)d_in[16];

    const int N   = in_sizes[2];
    const int E   = in_sizes[1] / 2;
    const int DIN = in_sizes[0] / N;   // 256
    const int L   = 6;
    const size_t NH = (size_t)N * 128;
    const int P   = (N + 3) / 4;
    const int NB  = (N + 1023) / 1024;

    float* out    = (float*)d_out;
    float* logits = out;
    float* loss   = out + (size_t)N * L;
    float* feats  = out + (size_t)N * L + 1;

    float* ws   = (float*)d_ws;
    float* h    = ws;                 // NH
    float* m    = ws + NH;            // NH
    float* agg  = ws + 2 * NH;        // NH
    float* part = ws + 3 * NH;        // P

    unsigned short* linP  = (unsigned short*)(part + P);   // 256*128
    unsigned short* w1P   = linP  + 32768;                 // 128*128
    unsigned short* w2P   = w1P   + 16384;
    unsigned short* wih1P = w2P   + 16384;                 // 128*384 packed as [4][384][32]
    unsigned short* whh1P = wih1P + 49152;
    unsigned short* wih2P = whh1P + 49152;
    unsigned short* whh2P = wih2P + 49152;

    int* off    = (int*)(whh2P + 49152);   // N+1
    int* cursor = off + (N + 1);           // N
    int* ssrc   = cursor + N;              // E
    int* bsum   = ssrc + E;                // NB
    int* bpre   = bsum + NB;               // NB

    const int* src = eidx;
    const int* dst = eidx + E;

    dim3 blk(256);
    unsigned egrid  = (unsigned)((E + 255) / 256);
    unsigned ngridW = (unsigned)((N + 3) / 4);
    unsigned gemmG  = (unsigned)((N + 63) / 64);
    unsigned gruG   = (unsigned)((N + 63) / 64);

    // CSR build (once; reused by both layers)
    hipMemsetAsync(cursor, 0, (size_t)N * sizeof(int), stream);
    hist_kernel<<<dim3(egrid), blk, 0, stream>>>(dst, cursor, E);
    scan1_kernel<<<dim3((unsigned)NB), dim3(1024), 0, stream>>>(cursor, off, bsum, N);
    scan2_kernel<<<dim3(1), dim3(1024), 0, stream>>>(bsum, bpre, NB);
    scan3_kernel<<<dim3((unsigned)NB), dim3(1024), 0, stream>>>(off, cursor, bpre, N, E);
    sort_kernel<<<dim3(egrid), blk, 0, stream>>>(src, dst, cursor, ssrc, E);

    // weight prepack to bf16 chunks
    prepack_kernel<<<dim3(128), blk, 0, stream>>>(lin_w, linP, DIN, 128, 0);
    prepack_kernel<<<dim3(64),  blk, 0, stream>>>(w1, w1P, 128, 128, 0);
    prepack_kernel<<<dim3(64),  blk, 0, stream>>>(w2, w2P, 128, 128, 0);
    prepack_kernel<<<dim3(192), blk, 0, stream>>>(wih1, wih1P, 128, 384, 1);
    prepack_kernel<<<dim3(192), blk, 0, stream>>>(whh1, whh1P, 128, 384, 1);
    prepack_kernel<<<dim3(192), blk, 0, stream>>>(wih2, wih2P, 128, 384, 1);
    prepack_kernel<<<dim3(192), blk, 0, stream>>>(whh2, whh2P, 128, 384, 1);

    // h = x @ lin_w + lin_b
    mfma_xw<<<dim3(gemmG), blk, 0, stream>>>(x, linP, lin_b, h, N, DIN);

    // ---- layer 1 ----
    mfma_xw<<<dim3(gemmG), blk, 0, stream>>>(h, w1P, nullptr, m, N, 128);
    gather_agg<<<dim3(ngridW), blk, 0, stream>>>(m, off, ssrc, agg, N);
    mfma_gru<1><<<dim3(gruG), dim3(1024), 0, stream>>>(agg, h, wih1P, whh1P, bih1, bhh1, h, N);

    // ---- layer 2 ----
    mfma_xw<<<dim3(gemmG), blk, 0, stream>>>(h, w2P, nullptr, m, N, 128);
    gather_agg<<<dim3(ngridW), blk, 0, stream>>>(m, off, ssrc, agg, N);
    mfma_gru<0><<<dim3(gruG), dim3(1024), 0, stream>>>(agg, h, wih2P, whh2P, bih2, bhh2, feats, N);

    // ---- classifier + loss ----
    cls_kernel<<<dim3(ngridW), blk, 0, stream>>>(feats, cls_w, cls_b, y, logits, part, N, 1.0f / (float)N);
    loss_reduce<<<dim3(1), dim3(1024), 0, stream>>>(part, loss, P);
}

// Round 7
// 364.911 us; speedup vs baseline: 6.9878x; 1.1824x over previous
//
#include <hip/hip_runtime.h>
#include <cstddef>
#include <cstdint>

typedef __attribute__((ext_vector_type(8))) short bf16x8;
typedef __attribute__((ext_vector_type(4))) float f32x4;
typedef __attribute__((ext_vector_type(8))) unsigned short u16x8;

__device__ inline unsigned short f2bf(float f) {
    unsigned u = __builtin_bit_cast(unsigned, f);
    u += 0x7FFF + ((u >> 16) & 1);          // round-to-nearest-even
    return (unsigned short)(u >> 16);
}
__device__ inline float bfbits_lo(unsigned v) { return __builtin_bit_cast(float, v << 16); }
__device__ inline float bfbits_hi(unsigned v) { return __builtin_bit_cast(float, v & 0xffff0000u); }

// XOR-swizzled byte offset into a [rows][32 bf16] LDS tile (64B rows).
__device__ inline int swzB(int row, int slot) {
    return row * 64 + ((slot ^ ((row >> 1) & 3)) << 4);
}
__device__ inline void stu(unsigned short* base, int u, u16x8 v) {
    *(u16x8*)((char*)base + swzB(u >> 2, u & 3)) = v;
}
__device__ inline bf16x8 ldu(const unsigned short* base, int row, int slot) {
    return *(const bf16x8*)((const char*)base + swzB(row, slot));
}

// ---------------- weight prepack: P[kc][c][kk] = Bop[k=kc*32+kk][c] ----------------
__global__ __launch_bounds__(256)
void prepack_kernel(const float* __restrict__ S, unsigned short* __restrict__ P,
                    int K, int C, int trans)
{
    int idx = blockIdx.x * 256 + threadIdx.x;
    if (idx >= K * C) return;
    int kk = idx & 31;
    int c  = (idx >> 5) % C;
    int kc = idx / (32 * C);
    int k  = kc * 32 + kk;
    float v = trans ? S[(size_t)c * K + k] : S[(size_t)k * C + c];
    P[idx] = f2bf(v);
}

// ---------------- MFMA GEMM: C[M,128] = A[M,K] @ W (+bias) ----------------
// OBF=0: C is float*. OBF=1: C is bf16 (ushort*).
template<int OBF>
__global__ __launch_bounds__(256)
void mfma_xw(const float* __restrict__ A, const unsigned short* __restrict__ P,
             const float* __restrict__ bias, void* __restrict__ Cout, int M, int K)
{
    __shared__ unsigned short Ab[64 * 32];
    __shared__ unsigned short Bb[128 * 32];
    const int tid  = threadIdx.x;
    const int l    = tid & 63;
    const int w    = tid >> 6;
    const int wr   = w >> 1, wc = w & 1;
    const int row0 = blockIdx.x * 64;

    f32x4 acc[2][4];
#pragma unroll
    for (int i = 0; i < 2; ++i)
#pragma unroll
        for (int j = 0; j < 4; ++j) acc[i][j] = (f32x4){0.f, 0.f, 0.f, 0.f};

    const int KC = K >> 5;
    for (int kc = 0; kc < KC; ++kc) {
        {   // stage A: 64 rows x 32 k, f32 -> bf16, swizzled
            int row = tid >> 2, slot = tid & 3, kpos = slot * 8;
            unsigned short u[8];
            if (row0 + row < M) {
                const float* src = &A[(size_t)(row0 + row) * K + kc * 32 + kpos];
                float4 v0 = *(const float4*)src;
                float4 v1 = *(const float4*)(src + 4);
                u[0]=f2bf(v0.x); u[1]=f2bf(v0.y); u[2]=f2bf(v0.z); u[3]=f2bf(v0.w);
                u[4]=f2bf(v1.x); u[5]=f2bf(v1.y); u[6]=f2bf(v1.z); u[7]=f2bf(v1.w);
            } else {
#pragma unroll
                for (int q = 0; q < 8; ++q) u[q] = 0;
            }
            stu(Ab, tid, *(u16x8*)u);
        }
        {   // stage B: copy packed chunk (128x32 bf16 = 512 units), swizzled
            const u16x8* src = (const u16x8*)(P + (size_t)kc * 4096);
            stu(Bb, tid * 2,     src[tid * 2]);
            stu(Bb, tid * 2 + 1, src[tid * 2 + 1]);
        }
        __syncthreads();
        bf16x8 af[2], bf[4];
#pragma unroll
        for (int rt = 0; rt < 2; ++rt)
            af[rt] = ldu(Ab, wr * 32 + rt * 16 + (l & 15), l >> 4);
#pragma unroll
        for (int ct = 0; ct < 4; ++ct)
            bf[ct] = ldu(Bb, wc * 64 + ct * 16 + (l & 15), l >> 4);
#pragma unroll
        for (int rt = 0; rt < 2; ++rt)
#pragma unroll
            for (int ct = 0; ct < 4; ++ct)
                acc[rt][ct] = __builtin_amdgcn_mfma_f32_16x16x32_bf16(af[rt], bf[ct], acc[rt][ct], 0, 0, 0);
        __syncthreads();
    }

#pragma unroll
    for (int rt = 0; rt < 2; ++rt)
#pragma unroll
        for (int ct = 0; ct < 4; ++ct) {
            int col = wc * 64 + ct * 16 + (l & 15);
            float bv = bias ? bias[col] : 0.0f;
#pragma unroll
            for (int j = 0; j < 4; ++j) {
                int row = row0 + wr * 32 + rt * 16 + (l >> 4) * 4 + j;
                if (row < M) {
                    float v = acc[rt][ct][j] + bv;
                    if (OBF) ((unsigned short*)Cout)[(size_t)row * 128 + col] = f2bf(v);
                    else     ((float*)Cout)[(size_t)row * 128 + col] = v;
                }
            }
        }
}

// ---------------- fused gi/gh GEMMs + GRU (agg input is bf16) ----------------
template<int ELU>
__global__ __launch_bounds__(1024)
void mfma_gru(const unsigned short* __restrict__ aggbf, const float* __restrict__ hin,
              const unsigned short* __restrict__ wihP, const unsigned short* __restrict__ whhP,
              const float* __restrict__ bih, const float* __restrict__ bhh,
              float* __restrict__ hout, int M)
{
    __shared__ unsigned short Aa[64 * 32];
    __shared__ unsigned short Ah[64 * 32];
    __shared__ unsigned short Bw[384 * 32];
    __shared__ unsigned short Bu[384 * 32];
    const int tid = threadIdx.x;
    const int l   = tid & 63;
    const int w   = tid >> 6;
    const int r   = w >> 3, g = w & 7;
    const int row0 = blockIdx.x * 64;

    f32x4 gi[3][2], gh[3][2];
#pragma unroll
    for (int gr = 0; gr < 3; ++gr)
#pragma unroll
        for (int rt = 0; rt < 2; ++rt) {
            gi[gr][rt] = (f32x4){0.f, 0.f, 0.f, 0.f};
            gh[gr][rt] = (f32x4){0.f, 0.f, 0.f, 0.f};
        }

    for (int kc = 0; kc < 4; ++kc) {
        const u16x8* sw = (const u16x8*)(wihP + (size_t)kc * 12288);
        const u16x8* su = (const u16x8*)(whhP + (size_t)kc * 12288);
        stu(Bw, tid, sw[tid]);
        stu(Bu, tid, su[tid]);
        if (tid < 512) {
            int u1 = 1024 + tid;
            stu(Bw, u1, sw[u1]);
            stu(Bu, u1, su[u1]);
        } else {
            int t2 = tid - 512;
            int mat = t2 >> 8;
            int t3 = t2 & 255;
            int row = t3 >> 2, slot = t3 & 3, kpos = slot * 8;
            unsigned short u[8];
            if (mat == 0) {
                if (row0 + row < M)
                    *(u16x8*)u = *(const u16x8*)&aggbf[(size_t)(row0 + row) * 128 + kc * 32 + kpos];
                else
#pragma unroll
                    for (int q = 0; q < 8; ++q) u[q] = 0;
                *(u16x8*)((char*)Aa + swzB(row, slot)) = *(u16x8*)u;
            } else {
                if (row0 + row < M) {
                    const float* src = &hin[(size_t)(row0 + row) * 128 + kc * 32 + kpos];
                    float4 v0 = *(const float4*)src;
                    float4 v1 = *(const float4*)(src + 4);
                    u[0]=f2bf(v0.x); u[1]=f2bf(v0.y); u[2]=f2bf(v0.z); u[3]=f2bf(v0.w);
                    u[4]=f2bf(v1.x); u[5]=f2bf(v1.y); u[6]=f2bf(v1.z); u[7]=f2bf(v1.w);
                } else {
#pragma unroll
                    for (int q = 0; q < 8; ++q) u[q] = 0;
                }
                *(u16x8*)((char*)Ah + swzB(row, slot)) = *(u16x8*)u;
            }
        }
        __syncthreads();

        bf16x8 aa[2], ah[2];
#pragma unroll
        for (int rt = 0; rt < 2; ++rt) {
            aa[rt] = ldu(Aa, r * 32 + rt * 16 + (l & 15), l >> 4);
            ah[rt] = ldu(Ah, r * 32 + rt * 16 + (l & 15), l >> 4);
        }
#pragma unroll
        for (int gr = 0; gr < 3; ++gr) {
            int c = gr * 128 + g * 16 + (l & 15);
            bf16x8 bw = ldu(Bw, c, l >> 4);
            bf16x8 bu = ldu(Bu, c, l >> 4);
#pragma unroll
            for (int rt = 0; rt < 2; ++rt) {
                gi[gr][rt] = __builtin_amdgcn_mfma_f32_16x16x32_bf16(aa[rt], bw, gi[gr][rt], 0, 0, 0);
                gh[gr][rt] = __builtin_amdgcn_mfma_f32_16x16x32_bf16(ah[rt], bu, gh[gr][rt], 0, 0, 0);
            }
        }
        __syncthreads();
    }

    {
        int unit = g * 16 + (l & 15);
        float bir = bih[unit], biz = bih[128 + unit], bin = bih[256 + unit];
        float bhr = bhh[unit], bhz = bhh[128 + unit], bhn = bhh[256 + unit];
#pragma unroll
        for (int rt = 0; rt < 2; ++rt)
#pragma unroll
            for (int j = 0; j < 4; ++j) {
                int row = row0 + r * 32 + rt * 16 + (l >> 4) * 4 + j;
                if (row >= M) continue;
                float ir  = gi[0][rt][j] + bir;
                float iz  = gi[1][rt][j] + biz;
                float in_ = gi[2][rt][j] + bin;
                float hr  = gh[0][rt][j] + bhr;
                float hz  = gh[1][rt][j] + bhz;
                float hn  = gh[2][rt][j] + bhn;
                float hv  = hin[(size_t)row * 128 + unit];
                float rr = 1.0f / (1.0f + expf(-(ir + hr)));
                float z  = 1.0f / (1.0f + expf(-(iz + hz)));
                float nn = tanhf(in_ + rr * hn);
                float o  = (1.0f - z) * nn + z * hv;
                if (ELU) o = (o > 0.0f) ? o : expm1f(o);
                hout[(size_t)row * 128 + unit] = o;
            }
    }
}

// ---------------- CSR build (counting sort of edges by dst) ----------------

__global__ __launch_bounds__(256)
void hist_kernel(const int* __restrict__ dst, int* __restrict__ deg, int E)
{
    int e = blockIdx.x * 256 + threadIdx.x;
    if (e < E) atomicAdd(&deg[dst[e]], 1);
}

__global__ __launch_bounds__(1024)
void scan1_kernel(const int* __restrict__ deg, int* __restrict__ off,
                  int* __restrict__ bsum, int N)
{
    __shared__ int wsum[16];
    const int t = threadIdx.x, lane = t & 63, w = t >> 6;
    const int i = blockIdx.x * 1024 + t;
    int v = (i < N) ? deg[i] : 0;
    int s = v;
#pragma unroll
    for (int o = 1; o < 64; o <<= 1) {
        int n = __shfl_up(s, o, 64);
        if (lane >= o) s += n;
    }
    if (lane == 63) wsum[w] = s;
    __syncthreads();
    if (w == 0) {
        int x = (lane < 16) ? wsum[lane] : 0;
#pragma unroll
        for (int o = 1; o < 16; o <<= 1) {
            int n = __shfl_up(x, o, 64);
            if (lane >= o) x += n;
        }
        if (lane < 16) wsum[lane] = x;
    }
    __syncthreads();
    int woff = (w == 0) ? 0 : wsum[w - 1];
    if (i < N) off[i] = woff + s - v;
    if (t == 0) bsum[blockIdx.x] = wsum[15];
}

__global__ __launch_bounds__(1024)
void scan2_kernel(const int* __restrict__ bsum, int* __restrict__ bpre, int NB)
{
    __shared__ int buf[1024];
    int t = threadIdx.x;
    int v = (t < NB) ? bsum[t] : 0;
    buf[t] = v;
    __syncthreads();
    for (int o = 1; o < 1024; o <<= 1) {
        int n = (t >= o) ? buf[t - o] : 0;
        __syncthreads();
        buf[t] += n;
        __syncthreads();
    }
    if (t < NB) bpre[t] = buf[t] - v;
}

__global__ __launch_bounds__(1024)
void scan3_kernel(int* __restrict__ off, int* __restrict__ cursor,
                  const int* __restrict__ bpre, int N, int E)
{
    int i = blockIdx.x * 1024 + threadIdx.x;
    if (i < N) {
        int v = off[i] + bpre[blockIdx.x];
        off[i] = v;
        cursor[i] = v;
    }
    if (i == 0) off[N] = E;
}

__global__ __launch_bounds__(256)
void sort_kernel(const int* __restrict__ src, const int* __restrict__ dst,
                 int* __restrict__ cursor, int* __restrict__ ssrc, int E)
{
    int e = blockIdx.x * 256 + threadIdx.x;
    if (e >= E) return;
    int pos = atomicAdd(&cursor[dst[e]], 1);
    ssrc[pos] = src[e];
}

// one wave per dst node, bf16 rows: half-wave (32 lanes x 8B) covers one 256B row;
// two edges in flight per wave + 2x unroll; merge halves with shfl_xor(32).
__global__ __launch_bounds__(256)
void gather_agg_bf(const unsigned short* __restrict__ m, const int* __restrict__ off,
                   const int* __restrict__ ssrc, unsigned short* __restrict__ agg, int N)
{
    int w = (blockIdx.x * 256 + threadIdx.x) >> 6;
    int lane = threadIdx.x & 63;
    if (w >= N) return;
    int half = lane >> 5, hl = lane & 31;
    int e0 = off[w], e1 = off[w + 1];
    float a0[4] = {0.f, 0.f, 0.f, 0.f};
    float a1[4] = {0.f, 0.f, 0.f, 0.f};
    int e = e0 + half;
    for (; e + 2 < e1; e += 4) {
        int s0 = ssrc[e], s1 = ssrc[e + 2];
        uint2 v0 = *(const uint2*)&m[(size_t)s0 * 128 + hl * 4];
        uint2 v1 = *(const uint2*)&m[(size_t)s1 * 128 + hl * 4];
        a0[0] += bfbits_lo(v0.x); a0[1] += bfbits_hi(v0.x);
        a0[2] += bfbits_lo(v0.y); a0[3] += bfbits_hi(v0.y);
        a1[0] += bfbits_lo(v1.x); a1[1] += bfbits_hi(v1.x);
        a1[2] += bfbits_lo(v1.y); a1[3] += bfbits_hi(v1.y);
    }
    if (e < e1) {
        int s0 = ssrc[e];
        uint2 v0 = *(const uint2*)&m[(size_t)s0 * 128 + hl * 4];
        a0[0] += bfbits_lo(v0.x); a0[1] += bfbits_hi(v0.x);
        a0[2] += bfbits_lo(v0.y); a0[3] += bfbits_hi(v0.y);
    }
    float o[4];
#pragma unroll
    for (int j = 0; j < 4; ++j) o[j] = a0[j] + a1[j];
#pragma unroll
    for (int j = 0; j < 4; ++j) o[j] += __shfl_xor(o[j], 32, 64);
    if (half == 0) {
        uint2 pk;
        pk.x = (unsigned)f2bf(o[0]) | ((unsigned)f2bf(o[1]) << 16);
        pk.y = (unsigned)f2bf(o[2]) | ((unsigned)f2bf(o[3]) << 16);
        *(uint2*)&agg[(size_t)w * 128 + hl * 4] = pk;
    }
}

// one wave per node: logits = h@W + b ; log_softmax ; per-block partial loss
__global__ __launch_bounds__(256)
void cls_kernel(const float* __restrict__ h, const float* __restrict__ W,
                const float* __restrict__ b, const int* __restrict__ y,
                float* __restrict__ logitsOut, float* __restrict__ partials,
                int N, float invN)
{
    __shared__ float pl[4];
    const int wid  = threadIdx.x >> 6;
    const int lane = threadIdx.x & 63;
    const int gw   = blockIdx.x * 4 + wid;
    if (threadIdx.x < 4) pl[threadIdx.x] = 0.0f;
    __syncthreads();
    if (gw < N) {
        float h0 = h[(size_t)gw * 128 + lane * 2];
        float h1 = h[(size_t)gw * 128 + lane * 2 + 1];
        float acc[6];
#pragma unroll
        for (int c = 0; c < 6; ++c)
            acc[c] = h0 * W[(lane * 2) * 6 + c] + h1 * W[(lane * 2 + 1) * 6 + c];
#pragma unroll
        for (int off = 32; off >= 1; off >>= 1)
#pragma unroll
            for (int c = 0; c < 6; ++c)
                acc[c] += __shfl_xor(acc[c], off, 64);
        float logit[6];
#pragma unroll
        for (int c = 0; c < 6; ++c) logit[c] = acc[c] + b[c];
#pragma unroll
        for (int c = 0; c < 6; ++c)
            if (lane == c) logitsOut[(size_t)gw * 6 + c] = logit[c];
        if (lane == 0) {
            float mx = logit[0];
#pragma unroll
            for (int c = 1; c < 6; ++c) mx = fmaxf(mx, logit[c]);
            float se = 0.0f;
#pragma unroll
            for (int c = 0; c < 6; ++c) se += expf(logit[c] - mx);
            float lse = mx + logf(se);
            int yy = y[gw];
            float ly = 0.0f;
#pragma unroll
            for (int c = 0; c < 6; ++c)
                if (yy == c) ly = logit[c];
            pl[wid] = (lse - ly) * invN;
        }
    }
    __syncthreads();
    if (threadIdx.x == 0)
        partials[blockIdx.x] = pl[0] + pl[1] + pl[2] + pl[3];
}

__global__ __launch_bounds__(1024)
void loss_reduce(const float* __restrict__ partials, float* __restrict__ loss, int P)
{
    __shared__ float buf[1024];
    float s = 0.0f;
    for (int i = threadIdx.x; i < (unsigned)P; i += 1024) s += partials[i];
    buf[threadIdx.x] = s;
    __syncthreads();
    for (int o = 512; o >= 1; o >>= 1) {
        if (threadIdx.x < (unsigned)o) buf[threadIdx.x] += buf[threadIdx.x + o];
        __syncthreads();
    }
    if (threadIdx.x == 0) loss[0] = buf[0];
}

extern "C" void kernel_launch(void* const* d_in, const int* in_sizes, int n_in,
                              void* d_out, int out_size, void* d_ws, size_t ws_size,
                              hipStream_t stream)
{
    const float* x     = (const float*)d_in[0];
    const int*   eidx  = (const int*)d_in[1];
    const int*   y     = (const int*)d_in[2];
    const float* lin_w = (const float*)d_in[3];
    const float* lin_b = (const float*)d_in[4];
    const float* w1    = (const float*)d_in[5];
    const float* wih1  = (const float*)d_in[6];
    const float* whh1  = (const float*)d_in[7];
    const float* bih1  = (const float*)d_in[8];
    const float* bhh1  = (const float*)d_in[9];
    const float* w2    = (const float*)d_in[10];
    const float* wih2  = (const float*)d_in[11];
    const float* whh2  = (const float*)d_in[12];
    const float* bih2  = (const float*)d_in[13];
    const float* bhh2  = (const float*)d_in[14];
    const float* cls_w = (const float*)d_in[15];
    const float* cls_b = (const float*)d_in[16];

    const int N   = in_sizes[2];
    const int E   = in_sizes[1] / 2;
    const int DIN = in_sizes[0] / N;   // 256
    const int L   = 6;
    const size_t NH = (size_t)N * 128;
    const int P   = (N + 3) / 4;
    const int NB  = (N + 1023) / 1024;

    float* out    = (float*)d_out;
    float* logits = out;
    float* loss   = out + (size_t)N * L;
    float* feats  = out + (size_t)N * L + 1;

    float* ws   = (float*)d_ws;
    float* h    = ws;                 // NH f32
    float* part = ws + NH;            // P f32

    unsigned short* m_bf   = (unsigned short*)(part + P);  // NH bf16
    unsigned short* agg_bf = m_bf + NH;                    // NH bf16
    unsigned short* linP   = agg_bf + NH;                  // 256*128
    unsigned short* w1P    = linP  + 32768;                // 128*128
    unsigned short* w2P    = w1P   + 16384;
    unsigned short* wih1P  = w2P   + 16384;                // [4][384][32]
    unsigned short* whh1P  = wih1P + 49152;
    unsigned short* wih2P  = whh1P + 49152;
    unsigned short* whh2P  = wih2P + 49152;

    int* off    = (int*)(whh2P + 49152);   // N+1
    int* cursor = off + (N + 1);           // N
    int* ssrc   = cursor + N;              // E
    int* bsum   = ssrc + E;                // NB
    int* bpre   = bsum + NB;               // NB

    const int* src = eidx;
    const int* dst = eidx + E;

    dim3 blk(256);
    unsigned egrid  = (unsigned)((E + 255) / 256);
    unsigned ngridW = (unsigned)((N + 3) / 4);
    unsigned gemmG  = (unsigned)((N + 63) / 64);
    unsigned gruG   = (unsigned)((N + 63) / 64);

    // CSR build (once; reused by both layers)
    hipMemsetAsync(cursor, 0, (size_t)N * sizeof(int), stream);
    hist_kernel<<<dim3(egrid), blk, 0, stream>>>(dst, cursor, E);
    scan1_kernel<<<dim3((unsigned)NB), dim3(1024), 0, stream>>>(cursor, off, bsum, N);
    scan2_kernel<<<dim3(1), dim3(1024), 0, stream>>>(bsum, bpre, NB);
    scan3_kernel<<<dim3((unsigned)NB), dim3(1024), 0, stream>>>(off, cursor, bpre, N, E);
    sort_kernel<<<dim3(egrid), blk, 0, stream>>>(src, dst, cursor, ssrc, E);

    // weight prepack to bf16 chunks
    prepack_kernel<<<dim3(128), blk, 0, stream>>>(lin_w, linP, DIN, 128, 0);
    prepack_kernel<<<dim3(64),  blk, 0, stream>>>(w1, w1P, 128, 128, 0);
    prepack_kernel<<<dim3(64),  blk, 0, stream>>>(w2, w2P, 128, 128, 0);
    prepack_kernel<<<dim3(192), blk, 0, stream>>>(wih1, wih1P, 128, 384, 1);
    prepack_kernel<<<dim3(192), blk, 0, stream>>>(whh1, whh1P, 128, 384, 1);
    prepack_kernel<<<dim3(192), blk, 0, stream>>>(wih2, wih2P, 128, 384, 1);
    prepack_kernel<<<dim3(192), blk, 0, stream>>>(whh2, whh2P, 128, 384, 1);

    // h = x @ lin_w + lin_b
    mfma_xw<0><<<dim3(gemmG), blk, 0, stream>>>(x, linP, lin_b, (void*)h, N, DIN);

    // ---- layer 1 ----
    mfma_xw<1><<<dim3(gemmG), blk, 0, stream>>>(h, w1P, nullptr, (void*)m_bf, N, 128);
    gather_agg_bf<<<dim3(ngridW), blk, 0, stream>>>(m_bf, off, ssrc, agg_bf, N);
    mfma_gru<1><<<dim3(gruG), dim3(1024), 0, stream>>>(agg_bf, h, wih1P, whh1P, bih1, bhh1, h, N);

    // ---- layer 2 ----
    mfma_xw<1><<<dim3(gemmG), blk, 0, stream>>>(h, w2P, nullptr, (void*)m_bf, N, 128);
    gather_agg_bf<<<dim3(ngridW), blk, 0, stream>>>(m_bf, off, ssrc, agg_bf, N);
    mfma_gru<0><<<dim3(gruG), dim3(1024), 0, stream>>>(agg_bf, h, wih2P, whh2P, bih2, bhh2, feats, N);

    // ---- classifier + loss ----
    cls_kernel<<<dim3(ngridW), blk, 0, stream>>>(feats, cls_w, cls_b, y, logits, part, N, 1.0f / (float)N);
    loss_reduce<<<dim3(1), dim3(1024), 0, stream>>>(part, loss, P);
}